// Round 2
// baseline (1613.877 us; speedup 1.0000x reference)
//
#include <hip/hip_runtime.h>
#include <hip/hip_bf16.h>

// GATv2 link predictor: N=50000, E=800000 (+N self loops), IN=128, HID=32, HEADS=4, OUT=64
// Inputs f32 (per reference dtypes); indices int32; output f32. Internal math f32.

#define DEVFN __device__ __forceinline__

// monotone float<->uint mapping for atomicMax on floats
DEVFN unsigned fmap(float f) {
  unsigned b = __float_as_uint(f);
  return (b & 0x80000000u) ? ~b : (b | 0x80000000u);
}
DEVFN float funmap(unsigned u) {
  unsigned b = (u & 0x80000000u) ? (u ^ 0x80000000u) : ~u;
  return __uint_as_float(b);
}

// ---------------- projection: Y[n][o] = B[o] + sum_i X[n][i] * W[i][o] ----------------
template <int DIN, int DOUT, int NPB>
__global__ __launch_bounds__(256) void proj_kernel(const float* __restrict__ X,
                                                   const float* __restrict__ W,
                                                   const float* __restrict__ B,
                                                   float* __restrict__ Y, int nN) {
  constexpr int NPI = 256 / DOUT;  // nodes per iteration
  constexpr int LDW = DIN + 4;     // padded row stride (f32 elems), keeps 16B align
  __shared__ __align__(16) float sWt[DOUT][LDW];
  __shared__ float sX[NPI][DIN];
  const int t = threadIdx.x;
  const int sub = t / DOUT, o = t % DOUT;
  for (int idx = t; idx < DIN * DOUT; idx += 256) {
    int i = idx / DOUT, oo = idx - i * DOUT;
    sWt[oo][i] = W[idx];  // transpose: sWt[o][i] = W[i*DOUT+o]
  }
  const float bias = B[o];
  const int base = blockIdx.x * NPB;
  for (int g = 0; g < NPB; g += NPI) {
    __syncthreads();
    for (int idx = t; idx < NPI * DIN; idx += 256) {
      int r = idx / DIN, c = idx - r * DIN;
      int node = base + g + r;
      sX[r][c] = (node < nN) ? X[(size_t)node * DIN + c] : 0.f;
    }
    __syncthreads();
    int node = base + g + sub;
    if (node < nN) {
      float acc = bias;
#pragma unroll
      for (int i = 0; i < DIN; i += 4) {
        float4 w4 = *(const float4*)&sWt[o][i];
        acc += sX[sub][i + 0] * w4.x + sX[sub][i + 1] * w4.y + sX[sub][i + 2] * w4.z +
               sX[sub][i + 3] * w4.w;
      }
      Y[(size_t)node * DOUT + o] = acc;
    }
  }
}

// ---------------- layer 1 edge passes (4 heads x 32 ch), wave per edge ----------------
__global__ __launch_bounds__(256) void edge1_logits(const float* __restrict__ xl,
                                                    const float* __restrict__ xr,
                                                    const int* __restrict__ ei,
                                                    const float* __restrict__ att,
                                                    float* __restrict__ lg,
                                                    unsigned* __restrict__ mu, int E, int ET) {
  int gid = blockIdx.x * 256 + threadIdx.x;
  int w = gid >> 6, l = gid & 63;
  if (w >= ET) return;
  int src, dst;
  if (w < E) { src = ei[w]; dst = ei[E + w]; } else { src = w - E; dst = src; }
  float2 a = *(const float2*)(xl + (size_t)src * 128 + 2 * l);
  float2 b = *(const float2*)(xr + (size_t)dst * 128 + 2 * l);
  float e0 = a.x + b.x; e0 = e0 > 0.f ? e0 : 0.2f * e0;
  float e1 = a.y + b.y; e1 = e1 > 0.f ? e1 : 0.2f * e1;
  float s = e0 * att[2 * l] + e1 * att[2 * l + 1];
#pragma unroll
  for (int o = 1; o < 16; o <<= 1) s += __shfl_xor(s, o);
  if ((l & 15) == 0) {
    int h = l >> 4;
    lg[(size_t)w * 4 + h] = s;
    atomicMax(&mu[(size_t)dst * 4 + h], fmap(s));
  }
}

__global__ __launch_bounds__(256) void edge1_accum(const float* __restrict__ xl,
                                                   const int* __restrict__ ei,
                                                   const float* __restrict__ lg,
                                                   const unsigned* __restrict__ mu,
                                                   float* __restrict__ den,
                                                   float* __restrict__ acc, int E, int ET) {
  int gid = blockIdx.x * 256 + threadIdx.x;
  int w = gid >> 6, l = gid & 63;
  if (w >= ET) return;
  int src, dst;
  if (w < E) { src = ei[w]; dst = ei[E + w]; } else { src = w - E; dst = src; }
  int h = l >> 4;
  float ex = expf(lg[(size_t)w * 4 + h] - funmap(mu[(size_t)dst * 4 + h]));
  if ((l & 15) == 0) unsafeAtomicAdd(&den[(size_t)dst * 4 + h], ex);
  float2 a = *(const float2*)(xl + (size_t)src * 128 + 2 * l);
  unsafeAtomicAdd(&acc[(size_t)dst * 128 + 2 * l], ex * a.x);
  unsafeAtomicAdd(&acc[(size_t)dst * 128 + 2 * l + 1], ex * a.y);
}

// ---------------- finalize layer 1: /denom + bias -> LN(128) -> ELU ----------------
__global__ __launch_bounds__(128) void fin1(const float* __restrict__ acc,
                                            const float* __restrict__ den,
                                            const float* __restrict__ bias,
                                            const float* __restrict__ g,
                                            const float* __restrict__ be,
                                            float* __restrict__ out, int nN) {
  int n = blockIdx.x, t = threadIdx.x;
  float v = acc[(size_t)n * 128 + t] / (den[(size_t)n * 4 + (t >> 5)] + 1e-16f) + bias[t];
  float s = v, s2 = v * v;
#pragma unroll
  for (int o = 1; o < 64; o <<= 1) { s += __shfl_xor(s, o); s2 += __shfl_xor(s2, o); }
  __shared__ float red[4];
  if ((t & 63) == 0) { red[(t >> 6) * 2] = s; red[(t >> 6) * 2 + 1] = s2; }
  __syncthreads();
  float S = red[0] + red[2], S2 = red[1] + red[3];
  float mn = S * (1.f / 128.f);
  float var = S2 * (1.f / 128.f) - mn * mn;
  float r = (v - mn) * rsqrtf(var + 1e-5f) * g[t] + be[t];
  r = r > 0.f ? r : expm1f(r);  // ELU
  out[(size_t)n * 128 + t] = r;
}

// ---------------- layer 2 edge passes (1 head x 64 ch), wave per edge ----------------
__global__ __launch_bounds__(256) void edge2_logits(const float* __restrict__ hl,
                                                    const float* __restrict__ hr,
                                                    const int* __restrict__ ei,
                                                    const float* __restrict__ att,
                                                    float* __restrict__ lg,
                                                    unsigned* __restrict__ mu, int E, int ET) {
  int gid = blockIdx.x * 256 + threadIdx.x;
  int w = gid >> 6, l = gid & 63;
  if (w >= ET) return;
  int src, dst;
  if (w < E) { src = ei[w]; dst = ei[E + w]; } else { src = w - E; dst = src; }
  float e = hl[(size_t)src * 64 + l] + hr[(size_t)dst * 64 + l];
  e = e > 0.f ? e : 0.2f * e;
  float s = e * att[l];
#pragma unroll
  for (int o = 1; o < 64; o <<= 1) s += __shfl_xor(s, o);
  if (l == 0) {
    lg[w] = s;
    atomicMax(&mu[dst], fmap(s));
  }
}

__global__ __launch_bounds__(256) void edge2_accum(const float* __restrict__ hl,
                                                   const int* __restrict__ ei,
                                                   const float* __restrict__ lg,
                                                   const unsigned* __restrict__ mu,
                                                   float* __restrict__ den,
                                                   float* __restrict__ acc, int E, int ET) {
  int gid = blockIdx.x * 256 + threadIdx.x;
  int w = gid >> 6, l = gid & 63;
  if (w >= ET) return;
  int src, dst;
  if (w < E) { src = ei[w]; dst = ei[E + w]; } else { src = w - E; dst = src; }
  float ex = expf(lg[w] - funmap(mu[dst]));
  if (l == 0) unsafeAtomicAdd(&den[dst], ex);
  unsafeAtomicAdd(&acc[(size_t)dst * 64 + l], ex * hl[(size_t)src * 64 + l]);
}

// ---------------- finalize layer 2: /denom + bias -> LN(64), in place ----------------
__global__ __launch_bounds__(64) void fin2(float* __restrict__ acc, const float* __restrict__ den,
                                           const float* __restrict__ bias,
                                           const float* __restrict__ g,
                                           const float* __restrict__ be, int nN) {
  int n = blockIdx.x, t = threadIdx.x;
  float v = acc[(size_t)n * 64 + t] / (den[n] + 1e-16f) + bias[t];
  float s = v, s2 = v * v;
#pragma unroll
  for (int o = 1; o < 64; o <<= 1) { s += __shfl_xor(s, o); s2 += __shfl_xor(s2, o); }
  float mn = s * (1.f / 64.f);
  float var = s2 * (1.f / 64.f) - mn * mn;
  float r = (v - mn) * rsqrtf(var + 1e-5f) * g[t] + be[t];
  acc[(size_t)n * 64 + t] = r;
}

// ---------------- decode: out[i] = dot(z[a], z[b]) ----------------
__global__ __launch_bounds__(256) void decode(const float* __restrict__ z,
                                              const int* __restrict__ eli,
                                              float* __restrict__ out, int EL) {
  int gid = blockIdx.x * 256 + threadIdx.x;
  int w = gid >> 6, l = gid & 63;
  if (w >= EL) return;
  int a = eli[w], b = eli[EL + w];
  float p = z[(size_t)a * 64 + l] * z[(size_t)b * 64 + l];
#pragma unroll
  for (int o = 1; o < 64; o <<= 1) p += __shfl_xor(p, o);
  if (l == 0) out[w] = p;
}

extern "C" void kernel_launch(void* const* d_in, const int* in_sizes, int n_in, void* d_out,
                              int out_size, void* d_ws, size_t ws_size, hipStream_t stream) {
  const float* x = (const float*)d_in[0];
  const int* ei = (const int*)d_in[1];
  const int* eli = (const int*)d_in[2];
  const float* W1l = (const float*)d_in[3];
  const float* b1l = (const float*)d_in[4];
  const float* W1r = (const float*)d_in[5];
  const float* b1r = (const float*)d_in[6];
  const float* att1 = (const float*)d_in[7];
  const float* bias1 = (const float*)d_in[8];
  const float* g1 = (const float*)d_in[9];
  const float* be1 = (const float*)d_in[10];
  const float* W2l = (const float*)d_in[11];
  const float* b2l = (const float*)d_in[12];
  const float* W2r = (const float*)d_in[13];
  const float* b2r = (const float*)d_in[14];
  const float* att2 = (const float*)d_in[15];
  const float* bias2 = (const float*)d_in[16];
  const float* g2 = (const float*)d_in[17];
  const float* be2 = (const float*)d_in[18];

  const int N = in_sizes[0] / 128;
  const int E = in_sizes[1] / 2;
  const int EL = in_sizes[2] / 2;
  const int ET = E + N;  // with self loops

  float* ws = (float*)d_ws;
  // layer-1 layout; layer-2 overlays dead regions
  size_t o_xl = 0;                        // N*128, reused as hl (N*64) + hr (N*64) in layer 2
  size_t o_xr = o_xl + (size_t)N * 128;   // N*128, becomes h after fin1
  size_t o_lg1 = o_xr + (size_t)N * 128;  // ET*4, reused as lg2 (ET)
  size_t o_m1 = o_lg1 + (size_t)ET * 4;   // N*4, reused as m2 (N)
  size_t o_d1 = o_m1 + (size_t)N * 4;     // N*4, reused as d2 (N)
  size_t o_a1 = o_d1 + (size_t)N * 4;     // N*128, reused as a2/z (N*64)
  size_t o_end = o_a1 + (size_t)N * 128;

  size_t o_hl = o_xl;
  size_t o_hr = o_xl + (size_t)N * 64;

  // zero m1/d1/a1
  hipMemsetAsync(ws + o_m1, 0, (o_end - o_m1) * sizeof(float), stream);

  const int projGrid = (N + 15) / 16;
  proj_kernel<128, 128, 16><<<projGrid, 256, 0, stream>>>(x, W1l, b1l, ws + o_xl, N);
  proj_kernel<128, 128, 16><<<projGrid, 256, 0, stream>>>(x, W1r, b1r, ws + o_xr, N);

  const int eBlocks = (int)(((size_t)ET * 64 + 255) / 256);
  edge1_logits<<<eBlocks, 256, 0, stream>>>(ws + o_xl, ws + o_xr, ei, att1, ws + o_lg1,
                                            (unsigned*)(ws + o_m1), E, ET);
  edge1_accum<<<eBlocks, 256, 0, stream>>>(ws + o_xl, ei, ws + o_lg1, (unsigned*)(ws + o_m1),
                                           ws + o_d1, ws + o_a1, E, ET);
  fin1<<<N, 128, 0, stream>>>(ws + o_a1, ws + o_d1, bias1, g1, be1, ws + o_xr, N);

  proj_kernel<128, 64, 16><<<projGrid, 256, 0, stream>>>(ws + o_xr, W2l, b2l, ws + o_hl, N);
  proj_kernel<128, 64, 16><<<projGrid, 256, 0, stream>>>(ws + o_xr, W2r, b2r, ws + o_hr, N);

  // zero m2/d2/a2 (reused regions)
  hipMemsetAsync(ws + o_m1, 0, (o_end - o_m1) * sizeof(float), stream);

  edge2_logits<<<eBlocks, 256, 0, stream>>>(ws + o_hl, ws + o_hr, ei, att2, ws + o_lg1,
                                            (unsigned*)(ws + o_m1), E, ET);
  edge2_accum<<<eBlocks, 256, 0, stream>>>(ws + o_hl, ei, ws + o_lg1, (unsigned*)(ws + o_m1),
                                           ws + o_d1, ws + o_a1, E, ET);
  fin2<<<N, 64, 0, stream>>>(ws + o_a1, ws + o_d1, bias2, g2, be2, N);

  const int dBlocks = (int)(((size_t)EL * 64 + 255) / 256);
  decode<<<dBlocks, 256, 0, stream>>>(ws + o_a1, eli, (float*)d_out, EL);
}

// Round 3
// 531.594 us; speedup vs baseline: 3.0359x; 3.0359x over previous
//
#include <hip/hip_runtime.h>
#include <hip/hip_bf16.h>

// GATv2 link predictor: N=50000, E=800000 (+N self loops), IN=128, HID=32, HEADS=4, OUT=64
// f32 in/out. Strategy: CSR by dst + fused flash-style online-softmax GAT layers (no float atomics).

#define DEVFN __device__ __forceinline__

// ---------------- projection: Y[n][o] = B[o] + sum_i X[n][i] * W[i][o] ----------------
template <int DIN, int DOUT, int NPB>
__global__ __launch_bounds__(256) void proj_kernel(const float* __restrict__ X,
                                                   const float* __restrict__ W,
                                                   const float* __restrict__ B,
                                                   float* __restrict__ Y, int nN) {
  constexpr int NPI = 256 / DOUT;  // nodes per iteration
  constexpr int LDW = DIN + 4;     // padded row stride
  __shared__ __align__(16) float sWt[DOUT][LDW];
  __shared__ float sX[NPI][DIN];
  const int t = threadIdx.x;
  const int sub = t / DOUT, o = t % DOUT;
  for (int idx = t; idx < DIN * DOUT; idx += 256) {
    int i = idx / DOUT, oo = idx - i * DOUT;
    sWt[oo][i] = W[idx];  // transpose
  }
  const float bias = B[o];
  const int base = blockIdx.x * NPB;
  for (int g = 0; g < NPB; g += NPI) {
    __syncthreads();
    for (int idx = t; idx < NPI * DIN; idx += 256) {
      int r = idx / DIN, c = idx - r * DIN;
      int node = base + g + r;
      sX[r][c] = (node < nN) ? X[(size_t)node * DIN + c] : 0.f;
    }
    __syncthreads();
    int node = base + g + sub;
    if (node < nN) {
      float acc = bias;
#pragma unroll
      for (int i = 0; i < DIN; i += 4) {
        float4 w4 = *(const float4*)&sWt[o][i];
        acc += sX[sub][i + 0] * w4.x + sX[sub][i + 1] * w4.y + sX[sub][i + 2] * w4.z +
               sX[sub][i + 3] * w4.w;
      }
      Y[(size_t)node * DOUT + o] = acc;
    }
  }
}

// ---------------- CSR build ----------------
__global__ __launch_bounds__(256) void deg_count(const int* __restrict__ ei, int* __restrict__ cnt,
                                                 int E, int ET) {
  int t = blockIdx.x * 256 + threadIdx.x;
  if (t >= ET) return;
  int dst = (t < E) ? ei[E + t] : (t - E);
  atomicAdd(&cnt[dst], 1);
}

__global__ __launch_bounds__(256) void scanA(const int* __restrict__ cnt, int* __restrict__ part,
                                             int N) {
  int i = blockIdx.x * 256 + threadIdx.x;
  int v = (i < N) ? cnt[i] : 0;
  __shared__ int wsm[4];
  int lane = threadIdx.x & 63, wid = threadIdx.x >> 6;
#pragma unroll
  for (int o = 1; o < 64; o <<= 1) v += __shfl_xor(v, o);
  if (lane == 0) wsm[wid] = v;
  __syncthreads();
  if (threadIdx.x == 0) part[blockIdx.x] = wsm[0] + wsm[1] + wsm[2] + wsm[3];
}

// exclusive scan of `part` in one 256-thread block (Bs <= 256); also writes rowptr[N]=total
__global__ __launch_bounds__(256) void scanB(int* __restrict__ part, int* __restrict__ rowptr,
                                             int Bs, int N) {
  int t = threadIdx.x;
  int v = (t < Bs) ? part[t] : 0;
  int lane = t & 63, wid = t >> 6;
  int s = v;
#pragma unroll
  for (int o = 1; o < 64; o <<= 1) {
    int u = __shfl_up(s, o);
    if (lane >= o) s += u;
  }
  __shared__ int wsm[4];
  if (lane == 63) wsm[wid] = s;
  __syncthreads();
  int woff = 0;
  for (int k = 0; k < wid; k++) woff += wsm[k];
  if (t < Bs) part[t] = woff + s - v;  // exclusive
  if (t == 0) rowptr[N] = wsm[0] + wsm[1] + wsm[2] + wsm[3];
}

__global__ __launch_bounds__(256) void scanC(const int* __restrict__ cnt,
                                             const int* __restrict__ part,
                                             int* __restrict__ rowptr, int N) {
  int i = blockIdx.x * 256 + threadIdx.x;
  int v = (i < N) ? cnt[i] : 0;
  int lane = threadIdx.x & 63, wid = threadIdx.x >> 6;
  int s = v;
#pragma unroll
  for (int o = 1; o < 64; o <<= 1) {
    int u = __shfl_up(s, o);
    if (lane >= o) s += u;
  }
  __shared__ int wsm[4];
  if (lane == 63) wsm[wid] = s;
  __syncthreads();
  int woff = 0;
  for (int k = 0; k < wid; k++) woff += wsm[k];
  if (i < N) rowptr[i] = part[blockIdx.x] + woff + s - v;
}

__global__ __launch_bounds__(256) void scatter_e(const int* __restrict__ ei,
                                                 const int* __restrict__ rowptr,
                                                 int* __restrict__ cur, int* __restrict__ adj,
                                                 int E, int ET) {
  int t = blockIdx.x * 256 + threadIdx.x;
  if (t >= ET) return;
  int src, dst;
  if (t < E) { src = ei[t]; dst = ei[E + t]; } else { src = t - E; dst = src; }
  int pos = atomicAdd(&cur[dst], 1);
  adj[rowptr[dst] + pos] = src;
}

// ---------------- fused GAT layer 1: wave per dst, online softmax, +LN+ELU ----------------
// reads xl (gather) and xr (own row); writes h in place of xr.
__global__ __launch_bounds__(256) void gat1(const float* __restrict__ xl, float* __restrict__ xr_h,
                                            const int* __restrict__ rowptr,
                                            const int* __restrict__ adj,
                                            const float* __restrict__ att,
                                            const float* __restrict__ bias,
                                            const float* __restrict__ g,
                                            const float* __restrict__ be, int N) {
  int w = blockIdx.x * 4 + (threadIdx.x >> 6);
  int l = threadIdx.x & 63;
  if (w >= N) return;
  float2 xrv = *(const float2*)(xr_h + (size_t)w * 128 + 2 * l);
  float a0 = att[2 * l], a1 = att[2 * l + 1];
  float m = -INFINITY, den = 0.f, accx = 0.f, accy = 0.f;
  int j0 = rowptr[w], j1 = rowptr[w + 1];

  auto proc = [&](float2 a) {
    float e0 = a.x + xrv.x; e0 = e0 > 0.f ? e0 : 0.2f * e0;
    float e1 = a.y + xrv.y; e1 = e1 > 0.f ? e1 : 0.2f * e1;
    float s = e0 * a0 + e1 * a1;
    s += __shfl_xor(s, 1); s += __shfl_xor(s, 2); s += __shfl_xor(s, 4); s += __shfl_xor(s, 8);
    float mn = fmaxf(m, s);
    float sc = __expf(m - mn);
    float p = __expf(s - mn);
    den = den * sc + p;
    accx = accx * sc + p * a.x;
    accy = accy * sc + p * a.y;
    m = mn;
  };

  int src = adj[j0];  // every dst has >=1 edge (self loop)
  float2 a = *(const float2*)(xl + (size_t)src * 128 + 2 * l);
  for (int j = j0 + 1; j < j1; ++j) {
    int sn = adj[j];
    float2 an = *(const float2*)(xl + (size_t)sn * 128 + 2 * l);  // prefetch next
    proc(a);
    a = an;
  }
  proc(a);

  float inv = 1.f / (den + 1e-16f);
  float vx = accx * inv + bias[2 * l];
  float vy = accy * inv + bias[2 * l + 1];
  // LayerNorm over 128 channels
  float s1 = vx + vy, s2 = vx * vx + vy * vy;
#pragma unroll
  for (int o = 1; o < 64; o <<= 1) { s1 += __shfl_xor(s1, o); s2 += __shfl_xor(s2, o); }
  float mu = s1 * (1.f / 128.f);
  float var = s2 * (1.f / 128.f) - mu * mu;
  float rs = rsqrtf(var + 1e-5f);
  float rx = (vx - mu) * rs * g[2 * l] + be[2 * l];
  float ry = (vy - mu) * rs * g[2 * l + 1] + be[2 * l + 1];
  rx = rx > 0.f ? rx : expm1f(rx);  // ELU
  ry = ry > 0.f ? ry : expm1f(ry);
  *(float2*)(xr_h + (size_t)w * 128 + 2 * l) = make_float2(rx, ry);
}

// ---------------- fused GAT layer 2: wave per dst (64 ch, 1 head), +LN ----------------
// reads hl (gather) and hr (own row); writes z in place of hr.
__global__ __launch_bounds__(256) void gat2(const float* __restrict__ hl, float* __restrict__ hr_z,
                                            const int* __restrict__ rowptr,
                                            const int* __restrict__ adj,
                                            const float* __restrict__ att,
                                            const float* __restrict__ bias,
                                            const float* __restrict__ g,
                                            const float* __restrict__ be, int N) {
  int w = blockIdx.x * 4 + (threadIdx.x >> 6);
  int l = threadIdx.x & 63;
  if (w >= N) return;
  float xrv = hr_z[(size_t)w * 64 + l];
  float av = att[l];
  float m = -INFINITY, den = 0.f, acc = 0.f;
  int j0 = rowptr[w], j1 = rowptr[w + 1];

  auto proc = [&](float a) {
    float e = a + xrv; e = e > 0.f ? e : 0.2f * e;
    float s = e * av;
#pragma unroll
    for (int o = 1; o < 64; o <<= 1) s += __shfl_xor(s, o);
    float mn = fmaxf(m, s);
    float sc = __expf(m - mn);
    float p = __expf(s - mn);
    den = den * sc + p;
    acc = acc * sc + p * a;
    m = mn;
  };

  int src = adj[j0];
  float a = hl[(size_t)src * 64 + l];
  for (int j = j0 + 1; j < j1; ++j) {
    int sn = adj[j];
    float an = hl[(size_t)sn * 64 + l];
    proc(a);
    a = an;
  }
  proc(a);

  float v = acc / (den + 1e-16f) + bias[l];
  float s1 = v, s2 = v * v;
#pragma unroll
  for (int o = 1; o < 64; o <<= 1) { s1 += __shfl_xor(s1, o); s2 += __shfl_xor(s2, o); }
  float mu = s1 * (1.f / 64.f);
  float var = s2 * (1.f / 64.f) - mu * mu;
  float r = (v - mu) * rsqrtf(var + 1e-5f) * g[l] + be[l];
  hr_z[(size_t)w * 64 + l] = r;
}

// ---------------- decode: out[i] = dot(z[a], z[b]) ----------------
__global__ __launch_bounds__(256) void decode(const float* __restrict__ z,
                                              const int* __restrict__ eli,
                                              float* __restrict__ out, int EL) {
  int gid = blockIdx.x * 256 + threadIdx.x;
  int w = gid >> 6, l = gid & 63;
  if (w >= EL) return;
  int a = eli[w], b = eli[EL + w];
  float p = z[(size_t)a * 64 + l] * z[(size_t)b * 64 + l];
#pragma unroll
  for (int o = 1; o < 64; o <<= 1) p += __shfl_xor(p, o);
  if (l == 0) out[w] = p;
}

extern "C" void kernel_launch(void* const* d_in, const int* in_sizes, int n_in, void* d_out,
                              int out_size, void* d_ws, size_t ws_size, hipStream_t stream) {
  const float* x = (const float*)d_in[0];
  const int* ei = (const int*)d_in[1];
  const int* eli = (const int*)d_in[2];
  const float* W1l = (const float*)d_in[3];
  const float* b1l = (const float*)d_in[4];
  const float* W1r = (const float*)d_in[5];
  const float* b1r = (const float*)d_in[6];
  const float* att1 = (const float*)d_in[7];
  const float* bias1 = (const float*)d_in[8];
  const float* g1 = (const float*)d_in[9];
  const float* be1 = (const float*)d_in[10];
  const float* W2l = (const float*)d_in[11];
  const float* b2l = (const float*)d_in[12];
  const float* W2r = (const float*)d_in[13];
  const float* b2r = (const float*)d_in[14];
  const float* att2 = (const float*)d_in[15];
  const float* bias2 = (const float*)d_in[16];
  const float* g2 = (const float*)d_in[17];
  const float* be2 = (const float*)d_in[18];

  const int N = in_sizes[0] / 128;
  const int E = in_sizes[1] / 2;
  const int EL = in_sizes[2] / 2;
  const int ET = E + N;  // with self loops

  float* ws = (float*)d_ws;
  size_t o_xl = 0;                       // N*128 floats; layer2: hl (N*64) + hr/z (N*64)
  size_t o_xr = o_xl + (size_t)N * 128;  // N*128 floats; becomes h after gat1
  int* ib = (int*)(ws + o_xr + (size_t)N * 128);
  int* cnt = ib;                 // N
  int* cur = ib + N;             // N
  int* rowptr = ib + 2 * N;      // N+1
  int* part = ib + 3 * N + 2;    // 256
  int* adj = ib + 3 * N + 258;   // ET

  const float* hl = ws + o_xl;
  float* hr_z = ws + o_xl + (size_t)N * 64;

  hipMemsetAsync(cnt, 0, 2 * N * sizeof(int), stream);  // cnt + cur

  const int projGrid = (N + 15) / 16;
  proj_kernel<128, 128, 16><<<projGrid, 256, 0, stream>>>(x, W1l, b1l, ws + o_xl, N);
  proj_kernel<128, 128, 16><<<projGrid, 256, 0, stream>>>(x, W1r, b1r, ws + o_xr, N);

  const int eB = (ET + 255) / 256;
  const int nB = (N + 255) / 256;
  deg_count<<<eB, 256, 0, stream>>>(ei, cnt, E, ET);
  scanA<<<nB, 256, 0, stream>>>(cnt, part, N);
  scanB<<<1, 256, 0, stream>>>(part, rowptr, nB, N);
  scanC<<<nB, 256, 0, stream>>>(cnt, part, rowptr, N);
  scatter_e<<<eB, 256, 0, stream>>>(ei, rowptr, cur, adj, E, ET);

  const int gB = (N + 3) / 4;
  gat1<<<gB, 256, 0, stream>>>(ws + o_xl, ws + o_xr, rowptr, adj, att1, bias1, g1, be1, N);

  proj_kernel<128, 64, 16><<<projGrid, 256, 0, stream>>>(ws + o_xr, W2l, b2l, (float*)hl, N);
  proj_kernel<128, 64, 16><<<projGrid, 256, 0, stream>>>(ws + o_xr, W2r, b2r, hr_z, N);

  gat2<<<gB, 256, 0, stream>>>(hl, hr_z, rowptr, adj, att2, bias2, g2, be2, N);

  const int dBlocks = (int)(((size_t)EL * 64 + 255) / 256);
  decode<<<dBlocks, 256, 0, stream>>>(hr_z, eli, (float*)d_out, EL);
}

// Round 4
// 335.862 us; speedup vs baseline: 4.8052x; 1.5828x over previous
//
#include <hip/hip_runtime.h>
#include <hip/hip_bf16.h>

// GATv2 link predictor: N=50000, E=800000 (+N self loops), IN=128, HID=32, HEADS=4, OUT=64
// f32 in/out. CSR + fused flash-style GAT layers; projections via bf16 MFMA GEMM.

#define DEVFN __device__ __forceinline__

typedef __attribute__((ext_vector_type(4))) float f32x4;
typedef __attribute__((ext_vector_type(8))) short bf16x8;

DEVFN unsigned short f2bf(float f) {  // RNE f32->bf16
  unsigned u = __float_as_uint(f);
  return (unsigned short)((u + 0x7fffu + ((u >> 16) & 1u)) >> 16);
}

// ---------------- fused dual-projection via MFMA ----------------
// Computes Ya = X*Wa + Ba and Yb = X*Wb + Bb.  X: [M x 128] f32, W: [128 x DOUT] f32.
// W staged in LDS as bf16, o-major ([o][k], 256B rows), XOR-swizzled byte^=((o&7)<<4).
// Each wave: 2 consecutive 16-row M-tiles, full 2*DOUT columns.
template <int DOUT>
__global__ __launch_bounds__(256) void proj_mfma(const float* __restrict__ X,
                                                 const float* __restrict__ Wa,
                                                 const float* __restrict__ Ba,
                                                 const float* __restrict__ Wb,
                                                 const float* __restrict__ Bb,
                                                 float* __restrict__ Ya, float* __restrict__ Yb,
                                                 int Mtiles) {
  constexpr int NPM = DOUT / 16;        // n-tiles per matrix
  constexpr unsigned MATB = DOUT * 256; // staged bytes per matrix
  __shared__ unsigned short sW[2 * DOUT * 128];
  const int t = threadIdx.x;
  for (int idx = t; idx < 128 * DOUT; idx += 256) {
    int k = idx / DOUT, o = idx - k * DOUT;
    unsigned byteoff = ((unsigned)(o * 256 + k * 2)) ^ ((unsigned)(o & 7) << 4);
    sW[byteoff >> 1] = f2bf(Wa[idx]);
    sW[(MATB + byteoff) >> 1] = f2bf(Wb[idx]);
  }
  __syncthreads();
  const int l = t & 63, wv = t >> 6;
  const int p = blockIdx.x * 4 + wv;
  const int mt0 = 2 * p;
  if (mt0 >= Mtiles) return;
  const bool two = (mt0 + 1) < Mtiles;
  const int r15 = l & 15, kq = l >> 4;

  bf16x8 a0[4], a1[4];
  {
    const float* px = X + ((size_t)(mt0 * 16 + r15)) * 128 + kq * 8;
#pragma unroll
    for (int ks = 0; ks < 4; ++ks) {
      f32x4 u = *(const f32x4*)(px + ks * 32);
      f32x4 v = *(const f32x4*)(px + ks * 32 + 4);
      bf16x8 fr;
      fr[0] = (short)f2bf(u[0]); fr[1] = (short)f2bf(u[1]);
      fr[2] = (short)f2bf(u[2]); fr[3] = (short)f2bf(u[3]);
      fr[4] = (short)f2bf(v[0]); fr[5] = (short)f2bf(v[1]);
      fr[6] = (short)f2bf(v[2]); fr[7] = (short)f2bf(v[3]);
      a0[ks] = fr;
      a1[ks] = fr;  // overwritten if two
    }
    if (two) {
      const float* py = X + ((size_t)((mt0 + 1) * 16 + r15)) * 128 + kq * 8;
#pragma unroll
      for (int ks = 0; ks < 4; ++ks) {
        f32x4 u = *(const f32x4*)(py + ks * 32);
        f32x4 v = *(const f32x4*)(py + ks * 32 + 4);
        bf16x8 fr;
        fr[0] = (short)f2bf(u[0]); fr[1] = (short)f2bf(u[1]);
        fr[2] = (short)f2bf(u[2]); fr[3] = (short)f2bf(u[3]);
        fr[4] = (short)f2bf(v[0]); fr[5] = (short)f2bf(v[1]);
        fr[6] = (short)f2bf(v[2]); fr[7] = (short)f2bf(v[3]);
        a1[ks] = fr;
      }
    }
  }

  for (int nt = 0; nt < 2 * NPM; ++nt) {
    const int mat = nt / NPM;
    const int o = (nt % NPM) * 16 + r15;  // output col / sW row
    bf16x8 b[4];
#pragma unroll
    for (int ks = 0; ks < 4; ++ks) {
      unsigned byteoff =
          (((unsigned)(o * 256 + (ks * 32 + kq * 8) * 2)) ^ ((unsigned)(o & 7) << 4)) +
          (unsigned)mat * MATB;
      b[ks] = *(const bf16x8*)((const char*)sW + byteoff);
    }
    f32x4 c0 = {0.f, 0.f, 0.f, 0.f}, c1 = {0.f, 0.f, 0.f, 0.f};
#pragma unroll
    for (int ks = 0; ks < 4; ++ks) {
      c0 = __builtin_amdgcn_mfma_f32_16x16x32_bf16(a0[ks], b[ks], c0, 0, 0, 0);
      if (two) c1 = __builtin_amdgcn_mfma_f32_16x16x32_bf16(a1[ks], b[ks], c1, 0, 0, 0);
    }
    float* Y = mat ? Yb : Ya;
    const float* Bv = mat ? Bb : Ba;
    const float bias = Bv[o];
    const int r0 = mt0 * 16 + 4 * kq;
#pragma unroll
    for (int r = 0; r < 4; ++r) Y[(size_t)(r0 + r) * DOUT + o] = c0[r] + bias;
    if (two) {
      const int r1 = (mt0 + 1) * 16 + 4 * kq;
#pragma unroll
      for (int r = 0; r < 4; ++r) Y[(size_t)(r1 + r) * DOUT + o] = c1[r] + bias;
    }
  }
}

// ---------------- CSR build ----------------
__global__ __launch_bounds__(256) void deg_count(const int* __restrict__ ei, int* __restrict__ cnt,
                                                 int E, int ET) {
  int t = blockIdx.x * 256 + threadIdx.x;
  if (t >= ET) return;
  int dst = (t < E) ? ei[E + t] : (t - E);
  atomicAdd(&cnt[dst], 1);
}

__global__ __launch_bounds__(256) void scanA(const int* __restrict__ cnt, int* __restrict__ part,
                                             int N) {
  int i = blockIdx.x * 256 + threadIdx.x;
  int v = (i < N) ? cnt[i] : 0;
  __shared__ int wsm[4];
  int lane = threadIdx.x & 63, wid = threadIdx.x >> 6;
#pragma unroll
  for (int o = 1; o < 64; o <<= 1) v += __shfl_xor(v, o);
  if (lane == 0) wsm[wid] = v;
  __syncthreads();
  if (threadIdx.x == 0) part[blockIdx.x] = wsm[0] + wsm[1] + wsm[2] + wsm[3];
}

__global__ __launch_bounds__(256) void scanB(int* __restrict__ part, int* __restrict__ rowptr,
                                             int Bs, int N) {
  int t = threadIdx.x;
  int v = (t < Bs) ? part[t] : 0;
  int lane = t & 63, wid = t >> 6;
  int s = v;
#pragma unroll
  for (int o = 1; o < 64; o <<= 1) {
    int u = __shfl_up(s, o);
    if (lane >= o) s += u;
  }
  __shared__ int wsm[4];
  if (lane == 63) wsm[wid] = s;
  __syncthreads();
  int woff = 0;
  for (int k = 0; k < wid; k++) woff += wsm[k];
  if (t < Bs) part[t] = woff + s - v;
  if (t == 0) rowptr[N] = wsm[0] + wsm[1] + wsm[2] + wsm[3];
}

__global__ __launch_bounds__(256) void scanC(const int* __restrict__ cnt,
                                             const int* __restrict__ part,
                                             int* __restrict__ rowptr, int N) {
  int i = blockIdx.x * 256 + threadIdx.x;
  int v = (i < N) ? cnt[i] : 0;
  int lane = threadIdx.x & 63, wid = threadIdx.x >> 6;
  int s = v;
#pragma unroll
  for (int o = 1; o < 64; o <<= 1) {
    int u = __shfl_up(s, o);
    if (lane >= o) s += u;
  }
  __shared__ int wsm[4];
  if (lane == 63) wsm[wid] = s;
  __syncthreads();
  int woff = 0;
  for (int k = 0; k < wid; k++) woff += wsm[k];
  if (i < N) rowptr[i] = part[blockIdx.x] + woff + s - v;
}

__global__ __launch_bounds__(256) void scatter_e(const int* __restrict__ ei,
                                                 const int* __restrict__ rowptr,
                                                 int* __restrict__ cur, int* __restrict__ adj,
                                                 int E, int ET) {
  int t = blockIdx.x * 256 + threadIdx.x;
  if (t >= ET) return;
  int src, dst;
  if (t < E) { src = ei[t]; dst = ei[E + t]; } else { src = t - E; dst = src; }
  int pos = atomicAdd(&cur[dst], 1);
  adj[rowptr[dst] + pos] = src;
}

// ---------------- fused GAT layer 1: wave per dst, online softmax, +LN+ELU ----------------
__global__ __launch_bounds__(256) void gat1(const float* __restrict__ xl, float* __restrict__ xr_h,
                                            const int* __restrict__ rowptr,
                                            const int* __restrict__ adj,
                                            const float* __restrict__ att,
                                            const float* __restrict__ bias,
                                            const float* __restrict__ g,
                                            const float* __restrict__ be, int N) {
  int w = blockIdx.x * 4 + (threadIdx.x >> 6);
  int l = threadIdx.x & 63;
  if (w >= N) return;
  float2 xrv = *(const float2*)(xr_h + (size_t)w * 128 + 2 * l);
  float a0 = att[2 * l], a1 = att[2 * l + 1];
  float m = -INFINITY, den = 0.f, accx = 0.f, accy = 0.f;
  int j0 = rowptr[w], j1 = rowptr[w + 1];

  auto proc = [&](float2 a) {
    float e0 = a.x + xrv.x; e0 = e0 > 0.f ? e0 : 0.2f * e0;
    float e1 = a.y + xrv.y; e1 = e1 > 0.f ? e1 : 0.2f * e1;
    float s = e0 * a0 + e1 * a1;
    s += __shfl_xor(s, 1); s += __shfl_xor(s, 2); s += __shfl_xor(s, 4); s += __shfl_xor(s, 8);
    float mn = fmaxf(m, s);
    float sc = __expf(m - mn);
    float p = __expf(s - mn);
    den = den * sc + p;
    accx = accx * sc + p * a.x;
    accy = accy * sc + p * a.y;
    m = mn;
  };

  int src = adj[j0];
  float2 a = *(const float2*)(xl + (size_t)src * 128 + 2 * l);
  for (int j = j0 + 1; j < j1; ++j) {
    int sn = adj[j];
    float2 an = *(const float2*)(xl + (size_t)sn * 128 + 2 * l);
    proc(a);
    a = an;
  }
  proc(a);

  float inv = 1.f / (den + 1e-16f);
  float vx = accx * inv + bias[2 * l];
  float vy = accy * inv + bias[2 * l + 1];
  float s1 = vx + vy, s2 = vx * vx + vy * vy;
#pragma unroll
  for (int o = 1; o < 64; o <<= 1) { s1 += __shfl_xor(s1, o); s2 += __shfl_xor(s2, o); }
  float mu = s1 * (1.f / 128.f);
  float var = s2 * (1.f / 128.f) - mu * mu;
  float rs = rsqrtf(var + 1e-5f);
  float rx = (vx - mu) * rs * g[2 * l] + be[2 * l];
  float ry = (vy - mu) * rs * g[2 * l + 1] + be[2 * l + 1];
  rx = rx > 0.f ? rx : expm1f(rx);
  ry = ry > 0.f ? ry : expm1f(ry);
  *(float2*)(xr_h + (size_t)w * 128 + 2 * l) = make_float2(rx, ry);
}

// ---------------- fused GAT layer 2: wave per dst (64 ch, 1 head), +LN ----------------
__global__ __launch_bounds__(256) void gat2(const float* __restrict__ hl, float* __restrict__ hr_z,
                                            const int* __restrict__ rowptr,
                                            const int* __restrict__ adj,
                                            const float* __restrict__ att,
                                            const float* __restrict__ bias,
                                            const float* __restrict__ g,
                                            const float* __restrict__ be, int N) {
  int w = blockIdx.x * 4 + (threadIdx.x >> 6);
  int l = threadIdx.x & 63;
  if (w >= N) return;
  float xrv = hr_z[(size_t)w * 64 + l];
  float av = att[l];
  float m = -INFINITY, den = 0.f, acc = 0.f;
  int j0 = rowptr[w], j1 = rowptr[w + 1];

  auto proc = [&](float a) {
    float e = a + xrv; e = e > 0.f ? e : 0.2f * e;
    float s = e * av;
#pragma unroll
    for (int o = 1; o < 64; o <<= 1) s += __shfl_xor(s, o);
    float mn = fmaxf(m, s);
    float sc = __expf(m - mn);
    float p = __expf(s - mn);
    den = den * sc + p;
    acc = acc * sc + p * a;
    m = mn;
  };

  int src = adj[j0];
  float a = hl[(size_t)src * 64 + l];
  for (int j = j0 + 1; j < j1; ++j) {
    int sn = adj[j];
    float an = hl[(size_t)sn * 64 + l];
    proc(a);
    a = an;
  }
  proc(a);

  float v = acc / (den + 1e-16f) + bias[l];
  float s1 = v, s2 = v * v;
#pragma unroll
  for (int o = 1; o < 64; o <<= 1) { s1 += __shfl_xor(s1, o); s2 += __shfl_xor(s2, o); }
  float mu = s1 * (1.f / 64.f);
  float var = s2 * (1.f / 64.f) - mu * mu;
  float r = (v - mu) * rsqrtf(var + 1e-5f) * g[l] + be[l];
  hr_z[(size_t)w * 64 + l] = r;
}

// ---------------- decode: out[i] = dot(z[a], z[b]) ----------------
__global__ __launch_bounds__(256) void decode(const float* __restrict__ z,
                                              const int* __restrict__ eli,
                                              float* __restrict__ out, int EL) {
  int gid = blockIdx.x * 256 + threadIdx.x;
  int w = gid >> 6, l = gid & 63;
  if (w >= EL) return;
  int a = eli[w], b = eli[EL + w];
  float p = z[(size_t)a * 64 + l] * z[(size_t)b * 64 + l];
#pragma unroll
  for (int o = 1; o < 64; o <<= 1) p += __shfl_xor(p, o);
  if (l == 0) out[w] = p;
}

extern "C" void kernel_launch(void* const* d_in, const int* in_sizes, int n_in, void* d_out,
                              int out_size, void* d_ws, size_t ws_size, hipStream_t stream) {
  const float* x = (const float*)d_in[0];
  const int* ei = (const int*)d_in[1];
  const int* eli = (const int*)d_in[2];
  const float* W1l = (const float*)d_in[3];
  const float* b1l = (const float*)d_in[4];
  const float* W1r = (const float*)d_in[5];
  const float* b1r = (const float*)d_in[6];
  const float* att1 = (const float*)d_in[7];
  const float* bias1 = (const float*)d_in[8];
  const float* g1 = (const float*)d_in[9];
  const float* be1 = (const float*)d_in[10];
  const float* W2l = (const float*)d_in[11];
  const float* b2l = (const float*)d_in[12];
  const float* W2r = (const float*)d_in[13];
  const float* b2r = (const float*)d_in[14];
  const float* att2 = (const float*)d_in[15];
  const float* bias2 = (const float*)d_in[16];
  const float* g2 = (const float*)d_in[17];
  const float* be2 = (const float*)d_in[18];

  const int N = in_sizes[0] / 128;
  const int E = in_sizes[1] / 2;
  const int EL = in_sizes[2] / 2;
  const int ET = E + N;

  float* ws = (float*)d_ws;
  size_t o_xl = 0;                       // N*128; layer2: hl (N*64) + hr/z (N*64)
  size_t o_xr = o_xl + (size_t)N * 128;  // N*128; becomes h after gat1
  int* ib = (int*)(ws + o_xr + (size_t)N * 128);
  int* cnt = ib;
  int* cur = ib + N;
  int* rowptr = ib + 2 * N;
  int* part = ib + 3 * N + 2;
  int* adj = ib + 3 * N + 258;

  const float* hl = ws + o_xl;
  float* hr_z = ws + o_xl + (size_t)N * 64;

  hipMemsetAsync(cnt, 0, 2 * N * sizeof(int), stream);

  const int Mtiles = (N + 15) / 16;                 // 3125
  const int pBlocks = ((Mtiles + 1) / 2 + 3) / 4;   // 391
  proj_mfma<128><<<pBlocks, 256, 0, stream>>>(x, W1l, b1l, W1r, b1r, ws + o_xl, ws + o_xr, Mtiles);

  const int eB = (ET + 255) / 256;
  const int nB = (N + 255) / 256;
  deg_count<<<eB, 256, 0, stream>>>(ei, cnt, E, ET);
  scanA<<<nB, 256, 0, stream>>>(cnt, part, N);
  scanB<<<1, 256, 0, stream>>>(part, rowptr, nB, N);
  scanC<<<nB, 256, 0, stream>>>(cnt, part, rowptr, N);
  scatter_e<<<eB, 256, 0, stream>>>(ei, rowptr, cur, adj, E, ET);

  const int gB = (N + 3) / 4;
  gat1<<<gB, 256, 0, stream>>>(ws + o_xl, ws + o_xr, rowptr, adj, att1, bias1, g1, be1, N);

  proj_mfma<64><<<pBlocks, 256, 0, stream>>>(ws + o_xr, W2l, b2l, W2r, b2r, (float*)hl, hr_z,
                                             Mtiles);

  gat2<<<gB, 256, 0, stream>>>(hl, hr_z, rowptr, adj, att2, bias2, g2, be2, N);

  const int dBlocks = (int)(((size_t)EL * 64 + 255) / 256);
  decode<<<dBlocks, 256, 0, stream>>>(hr_z, eli, (float*)d_out, EL);
}

// Round 6
// 281.121 us; speedup vs baseline: 5.7409x; 1.1947x over previous
//
#include <hip/hip_runtime.h>
#include <hip/hip_bf16.h>

// GATv2 link predictor: N=50000, E=800000 (+N self loops), IN=128, HID=32, HEADS=4, OUT=64
// f32 in/out. CSR + fused flash-style GAT layers (exact defer-max online softmax);
// projections via bf16 MFMA; gathered operands (xl, hl, z) stored f16 to halve traffic.
// Workspace (float units): xr_h [0,128N) | hr [128N,192N) | xl16(f16) [192N,256N)
//                          | z16(f16) [256N,288N) | ints [288N, ...)

#define DEVFN __device__ __forceinline__

typedef __attribute__((ext_vector_type(4))) float f32x4;
typedef __attribute__((ext_vector_type(8))) short bf16x8;
typedef _Float16 f16x2 __attribute__((ext_vector_type(2)));
typedef _Float16 f16x4 __attribute__((ext_vector_type(4)));

DEVFN unsigned short f2bf(float f) {  // RNE f32->bf16
  unsigned u = __float_as_uint(f);
  return (unsigned short)((u + 0x7fffu + ((u >> 16) & 1u)) >> 16);
}

// ---------------- fused dual-projection via MFMA ----------------
// Ya = X*Wa + Ba (written f16, will be gathered), Yb = X*Wb + Bb (written f32).
// W staged in LDS as bf16, o-major, XOR-swizzled byte^=((o&7)<<4).
template <int DOUT>
__global__ __launch_bounds__(256) void proj_mfma(const float* __restrict__ X,
                                                 const float* __restrict__ Wa,
                                                 const float* __restrict__ Ba,
                                                 const float* __restrict__ Wb,
                                                 const float* __restrict__ Bb,
                                                 _Float16* __restrict__ Ya,
                                                 float* __restrict__ Yb, int Mtiles) {
  constexpr int NPM = DOUT / 16;
  constexpr unsigned MATB = DOUT * 256;
  __shared__ unsigned short sW[2 * DOUT * 128];
  const int t = threadIdx.x;
  for (int idx = t; idx < 128 * DOUT; idx += 256) {
    int k = idx / DOUT, o = idx - k * DOUT;
    unsigned byteoff = ((unsigned)(o * 256 + k * 2)) ^ ((unsigned)(o & 7) << 4);
    sW[byteoff >> 1] = f2bf(Wa[idx]);
    sW[(MATB + byteoff) >> 1] = f2bf(Wb[idx]);
  }
  __syncthreads();
  const int l = t & 63, wv = t >> 6;
  const int p = blockIdx.x * 4 + wv;
  const int mt0 = 2 * p;
  if (mt0 >= Mtiles) return;
  const bool two = (mt0 + 1) < Mtiles;
  const int r15 = l & 15, kq = l >> 4;

  bf16x8 a0[4], a1[4];
  {
    const float* px = X + ((size_t)(mt0 * 16 + r15)) * 128 + kq * 8;
#pragma unroll
    for (int ks = 0; ks < 4; ++ks) {
      f32x4 u = *(const f32x4*)(px + ks * 32);
      f32x4 v = *(const f32x4*)(px + ks * 32 + 4);
      bf16x8 fr;
      fr[0] = (short)f2bf(u[0]); fr[1] = (short)f2bf(u[1]);
      fr[2] = (short)f2bf(u[2]); fr[3] = (short)f2bf(u[3]);
      fr[4] = (short)f2bf(v[0]); fr[5] = (short)f2bf(v[1]);
      fr[6] = (short)f2bf(v[2]); fr[7] = (short)f2bf(v[3]);
      a0[ks] = fr;
      a1[ks] = fr;
    }
    if (two) {
      const float* py = X + ((size_t)((mt0 + 1) * 16 + r15)) * 128 + kq * 8;
#pragma unroll
      for (int ks = 0; ks < 4; ++ks) {
        f32x4 u = *(const f32x4*)(py + ks * 32);
        f32x4 v = *(const f32x4*)(py + ks * 32 + 4);
        bf16x8 fr;
        fr[0] = (short)f2bf(u[0]); fr[1] = (short)f2bf(u[1]);
        fr[2] = (short)f2bf(u[2]); fr[3] = (short)f2bf(u[3]);
        fr[4] = (short)f2bf(v[0]); fr[5] = (short)f2bf(v[1]);
        fr[6] = (short)f2bf(v[2]); fr[7] = (short)f2bf(v[3]);
        a1[ks] = fr;
      }
    }
  }

  for (int nt = 0; nt < 2 * NPM; ++nt) {
    const int mat = nt / NPM;
    const int o = (nt % NPM) * 16 + r15;
    bf16x8 b[4];
#pragma unroll
    for (int ks = 0; ks < 4; ++ks) {
      unsigned byteoff =
          (((unsigned)(o * 256 + (ks * 32 + kq * 8) * 2)) ^ ((unsigned)(o & 7) << 4)) +
          (unsigned)mat * MATB;
      b[ks] = *(const bf16x8*)((const char*)sW + byteoff);
    }
    f32x4 c0 = {0.f, 0.f, 0.f, 0.f}, c1 = {0.f, 0.f, 0.f, 0.f};
#pragma unroll
    for (int ks = 0; ks < 4; ++ks) {
      c0 = __builtin_amdgcn_mfma_f32_16x16x32_bf16(a0[ks], b[ks], c0, 0, 0, 0);
      if (two) c1 = __builtin_amdgcn_mfma_f32_16x16x32_bf16(a1[ks], b[ks], c1, 0, 0, 0);
    }
    const float bias = (mat ? Bb : Ba)[o];
    const int r0 = mt0 * 16 + 4 * kq;
    const int r1 = (mt0 + 1) * 16 + 4 * kq;
    if (mat == 0) {
#pragma unroll
      for (int r = 0; r < 4; ++r) Ya[(size_t)(r0 + r) * DOUT + o] = (_Float16)(c0[r] + bias);
      if (two) {
#pragma unroll
        for (int r = 0; r < 4; ++r) Ya[(size_t)(r1 + r) * DOUT + o] = (_Float16)(c1[r] + bias);
      }
    } else {
#pragma unroll
      for (int r = 0; r < 4; ++r) Yb[(size_t)(r0 + r) * DOUT + o] = c0[r] + bias;
      if (two) {
#pragma unroll
        for (int r = 0; r < 4; ++r) Yb[(size_t)(r1 + r) * DOUT + o] = c1[r] + bias;
      }
    }
  }
}

// ---------------- CSR build ----------------
__global__ __launch_bounds__(256) void deg_count(const int* __restrict__ ei, int* __restrict__ cnt,
                                                 int E, int ET) {
  int t = blockIdx.x * 256 + threadIdx.x;
  if (t >= ET) return;
  int dst = (t < E) ? ei[E + t] : (t - E);
  atomicAdd(&cnt[dst], 1);
}

__global__ __launch_bounds__(256) void scanA(const int* __restrict__ cnt, int* __restrict__ part,
                                             int N) {
  int i = blockIdx.x * 256 + threadIdx.x;
  int v = (i < N) ? cnt[i] : 0;
  __shared__ int wsm[4];
  int lane = threadIdx.x & 63, wid = threadIdx.x >> 6;
#pragma unroll
  for (int o = 1; o < 64; o <<= 1) v += __shfl_xor(v, o);
  if (lane == 0) wsm[wid] = v;
  __syncthreads();
  if (threadIdx.x == 0) part[blockIdx.x] = wsm[0] + wsm[1] + wsm[2] + wsm[3];
}

__global__ __launch_bounds__(256) void scanB(int* __restrict__ part, int* __restrict__ rowptr,
                                             int Bs, int N) {
  int t = threadIdx.x;
  int v = (t < Bs) ? part[t] : 0;
  int lane = t & 63, wid = t >> 6;
  int s = v;
#pragma unroll
  for (int o = 1; o < 64; o <<= 1) {
    int u = __shfl_up(s, o);
    if (lane >= o) s += u;
  }
  __shared__ int wsm[4];
  if (lane == 63) wsm[wid] = s;
  __syncthreads();
  int woff = 0;
  for (int k = 0; k < wid; k++) woff += wsm[k];
  if (t < Bs) part[t] = woff + s - v;
  if (t == 0) rowptr[N] = wsm[0] + wsm[1] + wsm[2] + wsm[3];
}

__global__ __launch_bounds__(256) void scanC(const int* __restrict__ cnt,
                                             const int* __restrict__ part,
                                             int* __restrict__ rowptr, int N) {
  int i = blockIdx.x * 256 + threadIdx.x;
  int v = (i < N) ? cnt[i] : 0;
  int lane = threadIdx.x & 63, wid = threadIdx.x >> 6;
  int s = v;
#pragma unroll
  for (int o = 1; o < 64; o <<= 1) {
    int u = __shfl_up(s, o);
    if (lane >= o) s += u;
  }
  __shared__ int wsm[4];
  if (lane == 63) wsm[wid] = s;
  __syncthreads();
  int woff = 0;
  for (int k = 0; k < wid; k++) woff += wsm[k];
  if (i < N) rowptr[i] = part[blockIdx.x] + woff + s - v;
}

__global__ __launch_bounds__(256) void scatter_e(const int* __restrict__ ei,
                                                 const int* __restrict__ rowptr,
                                                 int* __restrict__ cur, int* __restrict__ adj,
                                                 int E, int ET) {
  int t = blockIdx.x * 256 + threadIdx.x;
  if (t >= ET) return;
  int src, dst;
  if (t < E) { src = ei[t]; dst = ei[E + t]; } else { src = t - E; dst = src; }
  int pos = atomicAdd(&cur[dst], 1);
  adj[rowptr[dst] + pos] = src;
}

// ---------------- fused GAT layer 1: wave per dst, defer-max online softmax, +LN+ELU --------
__global__ __launch_bounds__(256) void gat1(const _Float16* __restrict__ xl,
                                            float* __restrict__ xr_h,
                                            const int* __restrict__ rowptr,
                                            const int* __restrict__ adj,
                                            const float* __restrict__ att,
                                            const float* __restrict__ bias,
                                            const float* __restrict__ g,
                                            const float* __restrict__ be, int N) {
  int w = blockIdx.x * 4 + (threadIdx.x >> 6);
  int l = threadIdx.x & 63;
  if (w >= N) return;
  float2 xrv = *(const float2*)(xr_h + (size_t)w * 128 + 2 * l);
  float a0 = att[2 * l], a1 = att[2 * l + 1];
  float m = -1e30f, den = 0.f, accx = 0.f, accy = 0.f;
  int j0 = rowptr[w], j1 = rowptr[w + 1];

  auto proc = [&](f16x2 a2) {
    float ax = (float)a2[0], ay = (float)a2[1];
    float e0 = ax + xrv.x; e0 = fmaxf(e0, 0.2f * e0);
    float e1 = ay + xrv.y; e1 = fmaxf(e1, 0.2f * e1);
    float s = e0 * a0 + e1 * a1;
    s += __shfl_xor(s, 1); s += __shfl_xor(s, 2); s += __shfl_xor(s, 4); s += __shfl_xor(s, 8);
    if (s > m) {  // max grew: rescale (p = 1)
      float sc = __expf(m - s);
      den = den * sc + 1.f;
      accx = accx * sc + ax;
      accy = accy * sc + ay;
      m = s;
    } else {  // common case: 1 exp + 3 fma
      float p = __expf(s - m);
      den += p;
      accx = fmaf(p, ax, accx);
      accy = fmaf(p, ay, accy);
    }
  };

  int src = adj[j0];
  f16x2 a = *(const f16x2*)(xl + (size_t)src * 128 + 2 * l);
  for (int j = j0 + 1; j < j1; ++j) {
    int sn = adj[j];
    f16x2 an = *(const f16x2*)(xl + (size_t)sn * 128 + 2 * l);
    proc(a);
    a = an;
  }
  proc(a);

  float inv = 1.f / (den + 1e-16f);
  float vx = accx * inv + bias[2 * l];
  float vy = accy * inv + bias[2 * l + 1];
  float s1 = vx + vy, s2 = vx * vx + vy * vy;
#pragma unroll
  for (int o = 1; o < 64; o <<= 1) { s1 += __shfl_xor(s1, o); s2 += __shfl_xor(s2, o); }
  float mu = s1 * (1.f / 128.f);
  float var = s2 * (1.f / 128.f) - mu * mu;
  float rs = rsqrtf(var + 1e-5f);
  float rx = (vx - mu) * rs * g[2 * l] + be[2 * l];
  float ry = (vy - mu) * rs * g[2 * l + 1] + be[2 * l + 1];
  rx = rx > 0.f ? rx : expm1f(rx);
  ry = ry > 0.f ? ry : expm1f(ry);
  *(float2*)(xr_h + (size_t)w * 128 + 2 * l) = make_float2(rx, ry);
}

// ---------------- fused GAT layer 2: wave per dst, 4 edge-streams x 16 lanes, +LN -----------
__global__ __launch_bounds__(256) void gat2(const _Float16* __restrict__ hl,
                                            const float* __restrict__ hr,
                                            const int* __restrict__ rowptr,
                                            const int* __restrict__ adj,
                                            const float* __restrict__ att,
                                            const float* __restrict__ bias,
                                            const float* __restrict__ g,
                                            const float* __restrict__ be,
                                            _Float16* __restrict__ z, int N) {
  int w = blockIdx.x * 4 + (threadIdx.x >> 6);
  int l = threadIdx.x & 63;
  if (w >= N) return;
  int sub = l & 15, strm = l >> 4;
  float4 xrv = *(const float4*)(hr + (size_t)w * 64 + 4 * sub);
  float4 av = *(const float4*)(att + 4 * sub);
  float m = -1e30f, den = 0.f, ac0 = 0.f, ac1 = 0.f, ac2 = 0.f, ac3 = 0.f;
  int j0 = rowptr[w], j1 = rowptr[w + 1];

  for (int j = j0 + strm; j < j1; j += 4) {
    int src = adj[j];
    f16x4 a4 = *(const f16x4*)(hl + (size_t)src * 64 + 4 * sub);
    float b0 = (float)a4[0], b1 = (float)a4[1], b2 = (float)a4[2], b3 = (float)a4[3];
    float e0 = b0 + xrv.x; e0 = fmaxf(e0, 0.2f * e0);
    float e1 = b1 + xrv.y; e1 = fmaxf(e1, 0.2f * e1);
    float e2 = b2 + xrv.z; e2 = fmaxf(e2, 0.2f * e2);
    float e3 = b3 + xrv.w; e3 = fmaxf(e3, 0.2f * e3);
    float s = e0 * av.x + e1 * av.y + e2 * av.z + e3 * av.w;
    s += __shfl_xor(s, 1); s += __shfl_xor(s, 2); s += __shfl_xor(s, 4); s += __shfl_xor(s, 8);
    if (s > m) {
      float sc = __expf(m - s);
      den = den * sc + 1.f;
      ac0 = ac0 * sc + b0; ac1 = ac1 * sc + b1; ac2 = ac2 * sc + b2; ac3 = ac3 * sc + b3;
      m = s;
    } else {
      float p = __expf(s - m);
      den += p;
      ac0 = fmaf(p, b0, ac0); ac1 = fmaf(p, b1, ac1);
      ac2 = fmaf(p, b2, ac2); ac3 = fmaf(p, b3, ac3);
    }
  }
  // merge the 4 stream states (mergeable online-softmax states)
#pragma unroll
  for (int off = 16; off < 64; off <<= 1) {
    float om = __shfl_xor(m, off), oden = __shfl_xor(den, off);
    float o0 = __shfl_xor(ac0, off), o1 = __shfl_xor(ac1, off);
    float o2 = __shfl_xor(ac2, off), o3 = __shfl_xor(ac3, off);
    float mn = fmaxf(m, om);
    float sa = __expf(m - mn), sb = __expf(om - mn);
    den = den * sa + oden * sb;
    ac0 = ac0 * sa + o0 * sb; ac1 = ac1 * sa + o1 * sb;
    ac2 = ac2 * sa + o2 * sb; ac3 = ac3 * sa + o3 * sb;
    m = mn;
  }
  float inv = 1.f / (den + 1e-16f);
  float4 bv = *(const float4*)(bias + 4 * sub);
  float v0 = ac0 * inv + bv.x, v1 = ac1 * inv + bv.y;
  float v2 = ac2 * inv + bv.z, v3 = ac3 * inv + bv.w;
  float s1 = v0 + v1 + v2 + v3;
  float s2 = v0 * v0 + v1 * v1 + v2 * v2 + v3 * v3;
#pragma unroll
  for (int o = 1; o < 16; o <<= 1) { s1 += __shfl_xor(s1, o); s2 += __shfl_xor(s2, o); }
  float mu = s1 * (1.f / 64.f);
  float var = s2 * (1.f / 64.f) - mu * mu;
  float rs = rsqrtf(var + 1e-5f);
  float4 gv = *(const float4*)(g + 4 * sub);
  float4 bev = *(const float4*)(be + 4 * sub);
  if (strm == 0) {
    f16x4 zz;
    zz[0] = (_Float16)((v0 - mu) * rs * gv.x + bev.x);
    zz[1] = (_Float16)((v1 - mu) * rs * gv.y + bev.y);
    zz[2] = (_Float16)((v2 - mu) * rs * gv.z + bev.z);
    zz[3] = (_Float16)((v3 - mu) * rs * gv.w + bev.w);
    *(f16x4*)(z + (size_t)w * 64 + 4 * sub) = zz;
  }
}

// ---------------- decode: 4 pairs per wave, 16 lanes per pair ----------------
__global__ __launch_bounds__(256) void decode(const _Float16* __restrict__ z,
                                              const int* __restrict__ eli,
                                              float* __restrict__ out, int EL) {
  int wv = threadIdx.x >> 6, l = threadIdx.x & 63;
  int sub = l & 15;
  int pidx = (blockIdx.x * 4 + wv) * 4 + (l >> 4);
  if (pidx >= EL) return;
  int a = eli[pidx], b = eli[EL + pidx];
  f16x4 za = *(const f16x4*)(z + (size_t)a * 64 + 4 * sub);
  f16x4 zb = *(const f16x4*)(z + (size_t)b * 64 + 4 * sub);
  float p = (float)za[0] * (float)zb[0] + (float)za[1] * (float)zb[1] +
            (float)za[2] * (float)zb[2] + (float)za[3] * (float)zb[3];
  p += __shfl_xor(p, 1); p += __shfl_xor(p, 2); p += __shfl_xor(p, 4); p += __shfl_xor(p, 8);
  if (sub == 0) out[pidx] = p;
}

extern "C" void kernel_launch(void* const* d_in, const int* in_sizes, int n_in, void* d_out,
                              int out_size, void* d_ws, size_t ws_size, hipStream_t stream) {
  const float* x = (const float*)d_in[0];
  const int* ei = (const int*)d_in[1];
  const int* eli = (const int*)d_in[2];
  const float* W1l = (const float*)d_in[3];
  const float* b1l = (const float*)d_in[4];
  const float* W1r = (const float*)d_in[5];
  const float* b1r = (const float*)d_in[6];
  const float* att1 = (const float*)d_in[7];
  const float* bias1 = (const float*)d_in[8];
  const float* g1 = (const float*)d_in[9];
  const float* be1 = (const float*)d_in[10];
  const float* W2l = (const float*)d_in[11];
  const float* b2l = (const float*)d_in[12];
  const float* W2r = (const float*)d_in[13];
  const float* b2r = (const float*)d_in[14];
  const float* att2 = (const float*)d_in[15];
  const float* bias2 = (const float*)d_in[16];
  const float* g2 = (const float*)d_in[17];
  const float* be2 = (const float*)d_in[18];

  const int N = in_sizes[0] / 128;
  const int E = in_sizes[1] / 2;
  const int EL = in_sizes[2] / 2;
  const int ET = E + N;

  char* base = (char*)d_ws;
  float* xr_h = (float*)base;                                // [0,128N) f32: xr, then h
  float* hr = (float*)(base + (size_t)N * 128 * 4);          // [128N,192N) f32
  _Float16* xl16 = (_Float16*)(base + (size_t)N * 192 * 4);  // [192N,256N): N*128 f16 (xl/hl)
  _Float16* z16 = (_Float16*)(base + (size_t)N * 256 * 4);   // [256N,288N): N*64 f16 (z)
  int* ib = (int*)(base + (size_t)N * 288 * 4);
  int* cnt = ib;
  int* cur = ib + N;
  int* rowptr = ib + 2 * N;
  int* part = ib + 3 * N + 2;
  int* adj = ib + 3 * N + 258;

  hipMemsetAsync(cnt, 0, 2 * N * sizeof(int), stream);

  const int Mtiles = (N + 15) / 16;
  const int pBlocks = ((Mtiles + 1) / 2 + 3) / 4;
  proj_mfma<128><<<pBlocks, 256, 0, stream>>>(x, W1l, b1l, W1r, b1r, xl16, xr_h, Mtiles);

  const int eB = (ET + 255) / 256;
  const int nB = (N + 255) / 256;
  deg_count<<<eB, 256, 0, stream>>>(ei, cnt, E, ET);
  scanA<<<nB, 256, 0, stream>>>(cnt, part, N);
  scanB<<<1, 256, 0, stream>>>(part, rowptr, nB, N);
  scanC<<<nB, 256, 0, stream>>>(cnt, part, rowptr, N);
  scatter_e<<<eB, 256, 0, stream>>>(ei, rowptr, cur, adj, E, ET);

  const int gB = (N + 3) / 4;
  gat1<<<gB, 256, 0, stream>>>(xl16, xr_h, rowptr, adj, att1, bias1, g1, be1, N);

  proj_mfma<64><<<pBlocks, 256, 0, stream>>>(xr_h, W2l, b2l, W2r, b2r, xl16, hr, Mtiles);

  gat2<<<gB, 256, 0, stream>>>(xl16, hr, rowptr, adj, att2, bias2, g2, be2, z16, N);

  const int dBlocks = (EL + 15) / 16;
  decode<<<dBlocks, 256, 0, stream>>>(z16, eli, (float*)d_out, EL);
}

// Round 7
// 247.830 us; speedup vs baseline: 6.5120x; 1.1343x over previous
//
#include <hip/hip_runtime.h>
#include <hip/hip_bf16.h>

// GATv2 link predictor: N=50000, E=800000 (+N self loops), IN=128, HID=32, HEADS=4, OUT=64
// f32 in/out. CSR + fused flash-style GAT layers (branchless online softmax, multi-edge-stream);
// projections via bf16 MFMA; ALL intermediates 16-bit (f16 / bf16), softmax state f32.
// Workspace (bytes): xl16[0,256N) xr16[256N,512N) h_bf[512N,768N) hl16[768N,896N)
//                    hr16[896N,1024N) z16[1024N,1152N) ints[1152N,...)

#define DEVFN __device__ __forceinline__

typedef __attribute__((ext_vector_type(4))) float f32x4;
typedef __attribute__((ext_vector_type(8))) short bf16x8;
typedef _Float16 f16x2 __attribute__((ext_vector_type(2)));
typedef _Float16 f16x4 __attribute__((ext_vector_type(4)));
typedef _Float16 f16x8 __attribute__((ext_vector_type(8)));

DEVFN unsigned short f2bf(float f) {  // RNE f32->bf16
  unsigned u = __float_as_uint(f);
  return (unsigned short)((u + 0x7fffu + ((u >> 16) & 1u)) >> 16);
}

DEVFN bf16x8 load_frag(const float* p) {
  f32x4 u = *(const f32x4*)p;
  f32x4 v = *(const f32x4*)(p + 4);
  bf16x8 fr;
  fr[0] = (short)f2bf(u[0]); fr[1] = (short)f2bf(u[1]);
  fr[2] = (short)f2bf(u[2]); fr[3] = (short)f2bf(u[3]);
  fr[4] = (short)f2bf(v[0]); fr[5] = (short)f2bf(v[1]);
  fr[6] = (short)f2bf(v[2]); fr[7] = (short)f2bf(v[3]);
  return fr;
}
DEVFN bf16x8 load_frag(const unsigned short* p) { return *(const bf16x8*)p; }

// ---------------- fused dual-projection via MFMA ----------------
// Ya = X*Wa + Ba, Yb = X*Wb + Bb, both written f16.
// W staged in LDS as bf16, o-major, XOR-swizzled byte^=((o&7)<<4).
template <typename TIN, int DOUT>
__global__ __launch_bounds__(256) void proj_mfma(const TIN* __restrict__ X,
                                                 const float* __restrict__ Wa,
                                                 const float* __restrict__ Ba,
                                                 const float* __restrict__ Wb,
                                                 const float* __restrict__ Bb,
                                                 _Float16* __restrict__ Ya,
                                                 _Float16* __restrict__ Yb, int Mtiles) {
  constexpr int NPM = DOUT / 16;
  constexpr unsigned MATB = DOUT * 256;
  __shared__ unsigned short sW[2 * DOUT * 128];
  const int t = threadIdx.x;
  for (int idx = t; idx < 128 * DOUT; idx += 256) {
    int k = idx / DOUT, o = idx - k * DOUT;
    unsigned byteoff = ((unsigned)(o * 256 + k * 2)) ^ ((unsigned)(o & 7) << 4);
    sW[byteoff >> 1] = f2bf(Wa[idx]);
    sW[(MATB + byteoff) >> 1] = f2bf(Wb[idx]);
  }
  __syncthreads();
  const int l = t & 63, wv = t >> 6;
  const int p = blockIdx.x * 4 + wv;
  const int mt0 = 2 * p;
  if (mt0 >= Mtiles) return;
  const bool two = (mt0 + 1) < Mtiles;
  const int r15 = l & 15, kq = l >> 4;

  bf16x8 a0[4], a1[4];
  {
    const TIN* px = X + ((size_t)(mt0 * 16 + r15)) * 128 + kq * 8;
#pragma unroll
    for (int ks = 0; ks < 4; ++ks) {
      a0[ks] = load_frag(px + ks * 32);
      a1[ks] = a0[ks];
    }
    if (two) {
      const TIN* py = X + ((size_t)((mt0 + 1) * 16 + r15)) * 128 + kq * 8;
#pragma unroll
      for (int ks = 0; ks < 4; ++ks) a1[ks] = load_frag(py + ks * 32);
    }
  }

  for (int nt = 0; nt < 2 * NPM; ++nt) {
    const int mat = nt / NPM;
    const int o = (nt % NPM) * 16 + r15;
    bf16x8 b[4];
#pragma unroll
    for (int ks = 0; ks < 4; ++ks) {
      unsigned byteoff =
          (((unsigned)(o * 256 + (ks * 32 + kq * 8) * 2)) ^ ((unsigned)(o & 7) << 4)) +
          (unsigned)mat * MATB;
      b[ks] = *(const bf16x8*)((const char*)sW + byteoff);
    }
    f32x4 c0 = {0.f, 0.f, 0.f, 0.f}, c1 = {0.f, 0.f, 0.f, 0.f};
#pragma unroll
    for (int ks = 0; ks < 4; ++ks) {
      c0 = __builtin_amdgcn_mfma_f32_16x16x32_bf16(a0[ks], b[ks], c0, 0, 0, 0);
      if (two) c1 = __builtin_amdgcn_mfma_f32_16x16x32_bf16(a1[ks], b[ks], c1, 0, 0, 0);
    }
    _Float16* Y = mat ? Yb : Ya;
    const float bias = (mat ? Bb : Ba)[o];
    const int r0 = mt0 * 16 + 4 * kq;
#pragma unroll
    for (int r = 0; r < 4; ++r) Y[(size_t)(r0 + r) * DOUT + o] = (_Float16)(c0[r] + bias);
    if (two) {
      const int r1 = (mt0 + 1) * 16 + 4 * kq;
#pragma unroll
      for (int r = 0; r < 4; ++r) Y[(size_t)(r1 + r) * DOUT + o] = (_Float16)(c1[r] + bias);
    }
  }
}

// ---------------- CSR build ----------------
__global__ __launch_bounds__(256) void deg_count(const int* __restrict__ ei, int* __restrict__ cnt,
                                                 int E, int ET) {
  int t = blockIdx.x * 256 + threadIdx.x;
  if (t >= ET) return;
  int dst = (t < E) ? ei[E + t] : (t - E);
  atomicAdd(&cnt[dst], 1);
}

__global__ __launch_bounds__(256) void scanA(const int* __restrict__ cnt, int* __restrict__ part,
                                             int N) {
  int i = blockIdx.x * 256 + threadIdx.x;
  int v = (i < N) ? cnt[i] : 0;
  __shared__ int wsm[4];
  int lane = threadIdx.x & 63, wid = threadIdx.x >> 6;
#pragma unroll
  for (int o = 1; o < 64; o <<= 1) v += __shfl_xor(v, o);
  if (lane == 0) wsm[wid] = v;
  __syncthreads();
  if (threadIdx.x == 0) part[blockIdx.x] = wsm[0] + wsm[1] + wsm[2] + wsm[3];
}

__global__ __launch_bounds__(256) void scanB(int* __restrict__ part, int* __restrict__ rowptr,
                                             int Bs, int N) {
  int t = threadIdx.x;
  int v = (t < Bs) ? part[t] : 0;
  int lane = t & 63, wid = t >> 6;
  int s = v;
#pragma unroll
  for (int o = 1; o < 64; o <<= 1) {
    int u = __shfl_up(s, o);
    if (lane >= o) s += u;
  }
  __shared__ int wsm[4];
  if (lane == 63) wsm[wid] = s;
  __syncthreads();
  int woff = 0;
  for (int k = 0; k < wid; k++) woff += wsm[k];
  if (t < Bs) part[t] = woff + s - v;
  if (t == 0) rowptr[N] = wsm[0] + wsm[1] + wsm[2] + wsm[3];
}

__global__ __launch_bounds__(256) void scanC(const int* __restrict__ cnt,
                                             const int* __restrict__ part,
                                             int* __restrict__ rowptr, int N) {
  int i = blockIdx.x * 256 + threadIdx.x;
  int v = (i < N) ? cnt[i] : 0;
  int lane = threadIdx.x & 63, wid = threadIdx.x >> 6;
  int s = v;
#pragma unroll
  for (int o = 1; o < 64; o <<= 1) {
    int u = __shfl_up(s, o);
    if (lane >= o) s += u;
  }
  __shared__ int wsm[4];
  if (lane == 63) wsm[wid] = s;
  __syncthreads();
  int woff = 0;
  for (int k = 0; k < wid; k++) woff += wsm[k];
  if (i < N) rowptr[i] = part[blockIdx.x] + woff + s - v;
}

__global__ __launch_bounds__(256) void scatter_e(const int* __restrict__ ei,
                                                 const int* __restrict__ rowptr,
                                                 int* __restrict__ cur, int* __restrict__ adj,
                                                 int E, int ET) {
  int t = blockIdx.x * 256 + threadIdx.x;
  if (t >= ET) return;
  int src, dst;
  if (t < E) { src = ei[t]; dst = ei[E + t]; } else { src = t - E; dst = src; }
  int pos = atomicAdd(&cur[dst], 1);
  adj[rowptr[dst] + pos] = src;
}

// ---------------- fused GAT layer 1 ----------------
// wave per dst; 4 edge-streams x 16 lanes, 8 ch/lane; pk-f16 logit math + fdot2;
// branchless online softmax; stream merge; LN(128)+ELU; writes h as bf16.
__global__ __launch_bounds__(256) void gat1(const _Float16* __restrict__ xl,
                                            const _Float16* __restrict__ xr,
                                            unsigned short* __restrict__ h_out,
                                            const int* __restrict__ rowptr,
                                            const int* __restrict__ adj,
                                            const float* __restrict__ att,
                                            const float* __restrict__ bias,
                                            const float* __restrict__ g,
                                            const float* __restrict__ be, int N) {
  int w = blockIdx.x * 4 + (threadIdx.x >> 6);
  int l = threadIdx.x & 63;
  if (w >= N) return;
  int sub = l & 15, strm = l >> 4;
  f16x8 xr8 = *(const f16x8*)(xr + (size_t)w * 128 + 8 * sub);
  const f16x2* xr2 = (const f16x2*)&xr8;
  f16x2 at2[4];
#pragma unroll
  for (int q = 0; q < 4; ++q) {
    at2[q][0] = (_Float16)att[8 * sub + 2 * q];
    at2[q][1] = (_Float16)att[8 * sub + 2 * q + 1];
  }
  float m = -1e30f, den = 0.f;
  float acc[8] = {0.f, 0.f, 0.f, 0.f, 0.f, 0.f, 0.f, 0.f};
  int j0 = rowptr[w], j1 = rowptr[w + 1];

  auto proc = [&](f16x8 a8) {
    const f16x2* a2 = (const f16x2*)&a8;
    float s = 0.f;
#pragma unroll
    for (int q = 0; q < 4; ++q) {
      f16x2 e = a2[q] + xr2[q];
      f16x2 e2 = e * (_Float16)0.2f;
      e = __builtin_elementwise_max(e, e2);  // LeakyReLU(0.2), packed
      s = __builtin_amdgcn_fdot2(e, at2[q], s, false);
    }
    s += __shfl_xor(s, 1);
    s += __shfl_xor(s, 2);  // 4-lane head group now has full 32-ch logit
    float mn = fmaxf(m, s);
    float sa = __expf(m - mn), pb = __expf(s - mn);
    den = den * sa + pb;
#pragma unroll
    for (int c = 0; c < 8; ++c) acc[c] = acc[c] * sa + pb * (float)a8[c];
    m = mn;
  };

  int j = j0 + strm;
  if (j < j1) {
    f16x8 a = *(const f16x8*)(xl + (size_t)adj[j] * 128 + 8 * sub);
    for (j += 4; j < j1; j += 4) {
      f16x8 an = *(const f16x8*)(xl + (size_t)adj[j] * 128 + 8 * sub);
      proc(a);
      a = an;
    }
    proc(a);
  }

  // merge 4 stream states
#pragma unroll
  for (int off = 16; off < 64; off <<= 1) {
    float om = __shfl_xor(m, off), oden = __shfl_xor(den, off);
    float oa[8];
#pragma unroll
    for (int c = 0; c < 8; ++c) oa[c] = __shfl_xor(acc[c], off);
    float mn = fmaxf(m, om);
    float sa = __expf(m - mn), sb = __expf(om - mn);
    den = den * sa + oden * sb;
#pragma unroll
    for (int c = 0; c < 8; ++c) acc[c] = acc[c] * sa + oa[c] * sb;
    m = mn;
  }

  float inv = 1.f / (den + 1e-16f);
  float v[8], s1 = 0.f, s2 = 0.f;
#pragma unroll
  for (int c = 0; c < 8; ++c) {
    v[c] = acc[c] * inv + bias[8 * sub + c];
    s1 += v[c];
    s2 += v[c] * v[c];
  }
#pragma unroll
  for (int o = 1; o < 16; o <<= 1) { s1 += __shfl_xor(s1, o); s2 += __shfl_xor(s2, o); }
  float mu = s1 * (1.f / 128.f);
  float var = s2 * (1.f / 128.f) - mu * mu;
  float rs = rsqrtf(var + 1e-5f);
  if (strm == 0) {
    unsigned short o8[8];
#pragma unroll
    for (int c = 0; c < 8; ++c) {
      float r = (v[c] - mu) * rs * g[8 * sub + c] + be[8 * sub + c];
      r = r > 0.f ? r : expm1f(r);  // ELU
      o8[c] = f2bf(r);
    }
    *(uint4*)(h_out + (size_t)w * 128 + 8 * sub) = *(const uint4*)o8;
  }
}

// ---------------- fused GAT layer 2 ----------------
// wave per dst; 4 edge-streams x 16 lanes, 4 ch/lane; pk-f16 math; +LN; writes z f16.
__global__ __launch_bounds__(256) void gat2(const _Float16* __restrict__ hl,
                                            const _Float16* __restrict__ hr,
                                            const int* __restrict__ rowptr,
                                            const int* __restrict__ adj,
                                            const float* __restrict__ att,
                                            const float* __restrict__ bias,
                                            const float* __restrict__ g,
                                            const float* __restrict__ be,
                                            _Float16* __restrict__ z, int N) {
  int w = blockIdx.x * 4 + (threadIdx.x >> 6);
  int l = threadIdx.x & 63;
  if (w >= N) return;
  int sub = l & 15, strm = l >> 4;
  f16x4 xr4 = *(const f16x4*)(hr + (size_t)w * 64 + 4 * sub);
  const f16x2* xr2 = (const f16x2*)&xr4;
  f16x2 at2[2];
#pragma unroll
  for (int q = 0; q < 2; ++q) {
    at2[q][0] = (_Float16)att[4 * sub + 2 * q];
    at2[q][1] = (_Float16)att[4 * sub + 2 * q + 1];
  }
  float m = -1e30f, den = 0.f;
  float acc[4] = {0.f, 0.f, 0.f, 0.f};
  int j0 = rowptr[w], j1 = rowptr[w + 1];

  auto proc = [&](f16x4 a4) {
    const f16x2* a2 = (const f16x2*)&a4;
    float s = 0.f;
#pragma unroll
    for (int q = 0; q < 2; ++q) {
      f16x2 e = a2[q] + xr2[q];
      f16x2 e2 = e * (_Float16)0.2f;
      e = __builtin_elementwise_max(e, e2);
      s = __builtin_amdgcn_fdot2(e, at2[q], s, false);
    }
    s += __shfl_xor(s, 1); s += __shfl_xor(s, 2);
    s += __shfl_xor(s, 4); s += __shfl_xor(s, 8);
    float mn = fmaxf(m, s);
    float sa = __expf(m - mn), pb = __expf(s - mn);
    den = den * sa + pb;
#pragma unroll
    for (int c = 0; c < 4; ++c) acc[c] = acc[c] * sa + pb * (float)a4[c];
    m = mn;
  };

  int j = j0 + strm;
  if (j < j1) {
    f16x4 a = *(const f16x4*)(hl + (size_t)adj[j] * 64 + 4 * sub);
    for (j += 4; j < j1; j += 4) {
      f16x4 an = *(const f16x4*)(hl + (size_t)adj[j] * 64 + 4 * sub);
      proc(a);
      a = an;
    }
    proc(a);
  }

#pragma unroll
  for (int off = 16; off < 64; off <<= 1) {
    float om = __shfl_xor(m, off), oden = __shfl_xor(den, off);
    float oa[4];
#pragma unroll
    for (int c = 0; c < 4; ++c) oa[c] = __shfl_xor(acc[c], off);
    float mn = fmaxf(m, om);
    float sa = __expf(m - mn), sb = __expf(om - mn);
    den = den * sa + oden * sb;
#pragma unroll
    for (int c = 0; c < 4; ++c) acc[c] = acc[c] * sa + oa[c] * sb;
    m = mn;
  }

  float inv = 1.f / (den + 1e-16f);
  float v[4], s1 = 0.f, s2 = 0.f;
#pragma unroll
  for (int c = 0; c < 4; ++c) {
    v[c] = acc[c] * inv + bias[4 * sub + c];
    s1 += v[c];
    s2 += v[c] * v[c];
  }
#pragma unroll
  for (int o = 1; o < 16; o <<= 1) { s1 += __shfl_xor(s1, o); s2 += __shfl_xor(s2, o); }
  float mu = s1 * (1.f / 64.f);
  float var = s2 * (1.f / 64.f) - mu * mu;
  float rs = rsqrtf(var + 1e-5f);
  if (strm == 0) {
    f16x4 zz;
#pragma unroll
    for (int c = 0; c < 4; ++c)
      zz[c] = (_Float16)((v[c] - mu) * rs * g[4 * sub + c] + be[4 * sub + c]);
    *(f16x4*)(z + (size_t)w * 64 + 4 * sub) = zz;
  }
}

// ---------------- decode: 4 pairs per wave, 16 lanes per pair ----------------
__global__ __launch_bounds__(256) void decode(const _Float16* __restrict__ z,
                                              const int* __restrict__ eli,
                                              float* __restrict__ out, int EL) {
  int wv = threadIdx.x >> 6, l = threadIdx.x & 63;
  int sub = l & 15;
  int pidx = (blockIdx.x * 4 + wv) * 4 + (l >> 4);
  if (pidx >= EL) return;
  int a = eli[pidx], b = eli[EL + pidx];
  f16x4 za = *(const f16x4*)(z + (size_t)a * 64 + 4 * sub);
  f16x4 zb = *(const f16x4*)(z + (size_t)b * 64 + 4 * sub);
  float p = (float)za[0] * (float)zb[0] + (float)za[1] * (float)zb[1] +
            (float)za[2] * (float)zb[2] + (float)za[3] * (float)zb[3];
  p += __shfl_xor(p, 1); p += __shfl_xor(p, 2); p += __shfl_xor(p, 4); p += __shfl_xor(p, 8);
  if (sub == 0) out[pidx] = p;
}

extern "C" void kernel_launch(void* const* d_in, const int* in_sizes, int n_in, void* d_out,
                              int out_size, void* d_ws, size_t ws_size, hipStream_t stream) {
  const float* x = (const float*)d_in[0];
  const int* ei = (const int*)d_in[1];
  const int* eli = (const int*)d_in[2];
  const float* W1l = (const float*)d_in[3];
  const float* b1l = (const float*)d_in[4];
  const float* W1r = (const float*)d_in[5];
  const float* b1r = (const float*)d_in[6];
  const float* att1 = (const float*)d_in[7];
  const float* bias1 = (const float*)d_in[8];
  const float* g1 = (const float*)d_in[9];
  const float* be1 = (const float*)d_in[10];
  const float* W2l = (const float*)d_in[11];
  const float* b2l = (const float*)d_in[12];
  const float* W2r = (const float*)d_in[13];
  const float* b2r = (const float*)d_in[14];
  const float* att2 = (const float*)d_in[15];
  const float* bias2 = (const float*)d_in[16];
  const float* g2 = (const float*)d_in[17];
  const float* be2 = (const float*)d_in[18];

  const int N = in_sizes[0] / 128;
  const int E = in_sizes[1] / 2;
  const int EL = in_sizes[2] / 2;
  const int ET = E + N;

  char* base = (char*)d_ws;
  _Float16* xl16 = (_Float16*)base;                            // N*128 f16
  _Float16* xr16 = (_Float16*)(base + (size_t)N * 256);        // N*128 f16
  unsigned short* h_bf = (unsigned short*)(base + (size_t)N * 512);  // N*128 bf16
  _Float16* hl16 = (_Float16*)(base + (size_t)N * 768);        // N*64 f16
  _Float16* hr16 = (_Float16*)(base + (size_t)N * 896);        // N*64 f16
  _Float16* z16 = (_Float16*)(base + (size_t)N * 1024);        // N*64 f16
  int* ib = (int*)(base + (size_t)N * 1152);
  int* cnt = ib;
  int* cur = ib + N;
  int* rowptr = ib + 2 * N;
  int* part = ib + 3 * N + 2;
  int* adj = ib + 3 * N + 258;

  hipMemsetAsync(cnt, 0, 2 * N * sizeof(int), stream);

  const int Mtiles = (N + 15) / 16;
  const int pBlocks = ((Mtiles + 1) / 2 + 3) / 4;
  proj_mfma<float, 128><<<pBlocks, 256, 0, stream>>>(x, W1l, b1l, W1r, b1r, xl16, xr16, Mtiles);

  const int eB = (ET + 255) / 256;
  const int nB = (N + 255) / 256;
  deg_count<<<eB, 256, 0, stream>>>(ei, cnt, E, ET);
  scanA<<<nB, 256, 0, stream>>>(cnt, part, N);
  scanB<<<1, 256, 0, stream>>>(part, rowptr, nB, N);
  scanC<<<nB, 256, 0, stream>>>(cnt, part, rowptr, N);
  scatter_e<<<eB, 256, 0, stream>>>(ei, rowptr, cur, adj, E, ET);

  const int gB = (N + 3) / 4;
  gat1<<<gB, 256, 0, stream>>>(xl16, xr16, h_bf, rowptr, adj, att1, bias1, g1, be1, N);

  proj_mfma<unsigned short, 64>
      <<<pBlocks, 256, 0, stream>>>(h_bf, W2l, b2l, W2r, b2r, hl16, hr16, Mtiles);

  gat2<<<gB, 256, 0, stream>>>(hl16, hr16, rowptr, adj, att2, bias2, g2, be2, z16, N);

  const int dBlocks = (EL + 15) / 16;
  decode<<<dBlocks, 256, 0, stream>>>(z16, eli, (float*)d_out, EL);
}

// Round 9
// 223.169 us; speedup vs baseline: 7.2316x; 1.1105x over previous
//
#include <hip/hip_runtime.h>
#include <hip/hip_bf16.h>

// GATv2 link predictor: N=50000, E=800000 (+N self loops), IN=128, HID=32, HEADS=4, OUT=64
// f32 in/out. CSR + fused flash-style GAT layers; bf16 MFMA projections (swapped-operand,
// packed f16 stores, pre-swizzled W image staged by memcpy); gat kernels use pk-f16 math,
// f16 packed accumulators, DPP/ds_swizzle reductions. Softmax m/den state f32.

#define DEVFN __device__ __forceinline__

typedef __attribute__((ext_vector_type(4))) float f32x4;
typedef __attribute__((ext_vector_type(8))) short bf16x8;
typedef _Float16 f16x2 __attribute__((ext_vector_type(2)));
typedef _Float16 f16x8 __attribute__((ext_vector_type(8)));

DEVFN unsigned short f2bf(float f) {  // RNE f32->bf16
  unsigned u = __float_as_uint(f);
  return (unsigned short)((u + 0x7fffu + ((u >> 16) & 1u)) >> 16);
}

DEVFN f16x2 pkrtz(float a, float b) {  // v_cvt_pkrtz_f16_f32, bit-cast to f16x2
  auto r = __builtin_amdgcn_cvt_pkrtz(a, b);
  union { decltype(r) s; f16x2 d; } u;
  u.s = r;
  return u.d;
}

// cross-lane helpers: DPP quad-perm for xor1/xor2, ds_swizzle for xor4/8/16 (imm pattern)
template <int CTRL>
DEVFN float dpp_add(float s) {
  int x = __builtin_amdgcn_update_dpp(0, __float_as_int(s), CTRL, 0xF, 0xF, true);
  return s + __int_as_float(x);
}
template <int OFF>
DEVFN float swz_add(float s) {
  int x = __builtin_amdgcn_ds_swizzle(__float_as_int(s), OFF);
  return s + __int_as_float(x);
}
template <int OFF>
DEVFN float swz_f(float s) {
  return __int_as_float(__builtin_amdgcn_ds_swizzle(__float_as_int(s), OFF));
}
DEVFN int h2i(f16x2 v) { union { f16x2 h; int i; } u; u.h = v; return u.i; }
DEVFN f16x2 i2h(int i) { union { f16x2 h; int i; } u; u.i = i; return u.h; }
template <int OFF>
DEVFN f16x2 swz_h(f16x2 v) { return i2h(__builtin_amdgcn_ds_swizzle(h2i(v), OFF)); }

DEVFN bf16x8 load_frag(const float* p) {
  f32x4 u = *(const f32x4*)p;
  f32x4 v = *(const f32x4*)(p + 4);
  union { unsigned r[4]; bf16x8 h; } o;
  asm("v_cvt_pk_bf16_f32 %0, %1, %2" : "=v"(o.r[0]) : "v"(u[0]), "v"(u[1]));
  asm("v_cvt_pk_bf16_f32 %0, %1, %2" : "=v"(o.r[1]) : "v"(u[2]), "v"(u[3]));
  asm("v_cvt_pk_bf16_f32 %0, %1, %2" : "=v"(o.r[2]) : "v"(v[0]), "v"(v[1]));
  asm("v_cvt_pk_bf16_f32 %0, %1, %2" : "=v"(o.r[3]) : "v"(v[2]), "v"(v[3]));
  return o.h;
}
DEVFN bf16x8 load_frag(const unsigned short* p) { return *(const bf16x8*)p; }

// ---------------- prep_w: write bf16 o-major XOR-swizzled LDS image of all W to global ------
__global__ __launch_bounds__(256) void prep_w(const float* __restrict__ W1l,
                                              const float* __restrict__ W1r,
                                              const float* __restrict__ W2l,
                                              const float* __restrict__ W2r,
                                              unsigned short* __restrict__ wbuf) {
  int t = blockIdx.x * 256 + threadIdx.x;
  if (t < 16384) {  // W1: [128][128]
    int k = t >> 7, o = t & 127;
    unsigned off = ((unsigned)(o * 256 + k * 2)) ^ ((unsigned)(o & 7) << 4);
    wbuf[off >> 1] = f2bf(W1l[t]);
    wbuf[16384 + (off >> 1)] = f2bf(W1r[t]);
  }
  if (t < 8192) {  // W2: [128][64]
    int k = t >> 6, o = t & 63;
    unsigned off = ((unsigned)(o * 256 + k * 2)) ^ ((unsigned)(o & 7) << 4);
    wbuf[32768 + (off >> 1)] = f2bf(W2l[t]);
    wbuf[40960 + (off >> 1)] = f2bf(W2r[t]);
  }
}

// ---------------- fused dual-projection via MFMA (swapped operands) ----------------
// Ya = X*Wa + Ba, Yb = X*Wb + Bb, both f16. A-operand = W (from pre-swizzled LDS image),
// B-operand = X rows. C layout: row = output channel o, col = node -> packed 8B stores.
template <typename TIN, int DOUT>
__global__ __launch_bounds__(256) void proj_mfma(const TIN* __restrict__ X,
                                                 const unsigned short* __restrict__ wsrc,
                                                 const float* __restrict__ Ba,
                                                 const float* __restrict__ Bb,
                                                 _Float16* __restrict__ Ya,
                                                 _Float16* __restrict__ Yb, int Mtiles) {
  constexpr int NPM = DOUT / 16;
  constexpr unsigned MATB = DOUT * 256;  // bytes per matrix image
  __shared__ unsigned short sW[2 * DOUT * 128];
  const int t = threadIdx.x;
  {  // stage: pure memcpy of the pre-swizzled image
    const char* gsrc = (const char*)wsrc;
    char* lds = (char*)sW;
    for (unsigned off = t * 16; off < 2 * MATB; off += 256 * 16)
      *(uint4*)(lds + off) = *(const uint4*)(gsrc + off);
  }
  __syncthreads();
  const int l = t & 63, wv = t >> 6;
  const int p = blockIdx.x * 4 + wv;
  const int mt0 = 2 * p;
  if (mt0 >= Mtiles) return;
  const bool two = (mt0 + 1) < Mtiles;
  const int r15 = l & 15, kq = l >> 4;

  bf16x8 a0[4], a1[4];
  {
    const TIN* px = X + ((size_t)(mt0 * 16 + r15)) * 128 + kq * 8;
#pragma unroll
    for (int ks = 0; ks < 4; ++ks) {
      a0[ks] = load_frag(px + ks * 32);
      a1[ks] = a0[ks];
    }
    if (two) {
      const TIN* py = X + ((size_t)((mt0 + 1) * 16 + r15)) * 128 + kq * 8;
#pragma unroll
      for (int ks = 0; ks < 4; ++ks) a1[ks] = load_frag(py + ks * 32);
    }
  }

  for (int nt = 0; nt < 2 * NPM; ++nt) {
    const int mat = nt / NPM;
    const int o = (nt % NPM) * 16 + r15;
    bf16x8 b[4];
#pragma unroll
    for (int ks = 0; ks < 4; ++ks) {
      unsigned byteoff =
          (((unsigned)(o * 256 + (ks * 32 + kq * 8) * 2)) ^ ((unsigned)(o & 7) << 4)) +
          (unsigned)mat * MATB;
      b[ks] = *(const bf16x8*)((const char*)sW + byteoff);
    }
    f32x4 c0 = {0.f, 0.f, 0.f, 0.f}, c1 = {0.f, 0.f, 0.f, 0.f};
#pragma unroll
    for (int ks = 0; ks < 4; ++ks) {
      c0 = __builtin_amdgcn_mfma_f32_16x16x32_bf16(b[ks], a0[ks], c0, 0, 0, 0);  // swapped
      if (two) c1 = __builtin_amdgcn_mfma_f32_16x16x32_bf16(b[ks], a1[ks], c1, 0, 0, 0);
    }
    _Float16* Y = mat ? Yb : Ya;
    const float* Bv = mat ? Bb : Ba;
    const int obase = (nt % NPM) * 16 + 4 * kq;
    float4 b4 = *(const float4*)(Bv + obase);
    union { f16x2 h[2]; uint2 u; } pk;
    pk.h[0] = pkrtz(c0[0] + b4.x, c0[1] + b4.y);
    pk.h[1] = pkrtz(c0[2] + b4.z, c0[3] + b4.w);
    *(uint2*)(Y + (size_t)(mt0 * 16 + r15) * DOUT + obase) = pk.u;
    if (two) {
      pk.h[0] = pkrtz(c1[0] + b4.x, c1[1] + b4.y);
      pk.h[1] = pkrtz(c1[2] + b4.z, c1[3] + b4.w);
      *(uint2*)(Y + (size_t)((mt0 + 1) * 16 + r15) * DOUT + obase) = pk.u;
    }
  }
}

// ---------------- CSR build ----------------
__global__ __launch_bounds__(256) void deg_count(const int* __restrict__ ei, int* __restrict__ cnt,
                                                 int E, int ET) {
  int t = blockIdx.x * 256 + threadIdx.x;
  if (t >= ET) return;
  int dst = (t < E) ? ei[E + t] : (t - E);
  atomicAdd(&cnt[dst], 1);
}

__global__ __launch_bounds__(256) void scanA(const int* __restrict__ cnt, int* __restrict__ part,
                                             int N) {
  int i = blockIdx.x * 256 + threadIdx.x;
  int v = (i < N) ? cnt[i] : 0;
  __shared__ int wsm[4];
  int lane = threadIdx.x & 63, wid = threadIdx.x >> 6;
#pragma unroll
  for (int o = 1; o < 64; o <<= 1) v += __shfl_xor(v, o);
  if (lane == 0) wsm[wid] = v;
  __syncthreads();
  if (threadIdx.x == 0) part[blockIdx.x] = wsm[0] + wsm[1] + wsm[2] + wsm[3];
}

__global__ __launch_bounds__(256) void scanB(int* __restrict__ part, int* __restrict__ rowptr,
                                             int Bs, int N) {
  int t = threadIdx.x;
  int v = (t < Bs) ? part[t] : 0;
  int lane = t & 63, wid = t >> 6;
  int s = v;
#pragma unroll
  for (int o = 1; o < 64; o <<= 1) {
    int u = __shfl_up(s, o);
    if (lane >= o) s += u;
  }
  __shared__ int wsm[4];
  if (lane == 63) wsm[wid] = s;
  __syncthreads();
  int woff = 0;
  for (int k = 0; k < wid; k++) woff += wsm[k];
  if (t < Bs) part[t] = woff + s - v;
  if (t == 0) rowptr[N] = wsm[0] + wsm[1] + wsm[2] + wsm[3];
}

__global__ __launch_bounds__(256) void scanC(const int* __restrict__ cnt,
                                             const int* __restrict__ part,
                                             int* __restrict__ rowptr, int N) {
  int i = blockIdx.x * 256 + threadIdx.x;
  int v = (i < N) ? cnt[i] : 0;
  int lane = threadIdx.x & 63, wid = threadIdx.x >> 6;
  int s = v;
#pragma unroll
  for (int o = 1; o < 64; o <<= 1) {
    int u = __shfl_up(s, o);
    if (lane >= o) s += u;
  }
  __shared__ int wsm[4];
  if (lane == 63) wsm[wid] = s;
  __syncthreads();
  int woff = 0;
  for (int k = 0; k < wid; k++) woff += wsm[k];
  if (i < N) rowptr[i] = part[blockIdx.x] + woff + s - v;
}

__global__ __launch_bounds__(256) void scatter_e(const int* __restrict__ ei,
                                                 const int* __restrict__ rowptr,
                                                 int* __restrict__ cur, int* __restrict__ adj,
                                                 int E, int ET) {
  int t = blockIdx.x * 256 + threadIdx.x;
  if (t >= ET) return;
  int src, dst;
  if (t < E) { src = ei[t]; dst = ei[E + t]; } else { src = t - E; dst = src; }
  int pos = atomicAdd(&cur[dst], 1);
  adj[rowptr[dst] + pos] = src;
}

// ---------------- fused GAT layer 1: wave/dst, 4 streams x 16 lanes, 8ch/lane --------------
__global__ __launch_bounds__(256) void gat1(const _Float16* __restrict__ xl,
                                            const _Float16* __restrict__ xr,
                                            unsigned short* __restrict__ h_out,
                                            const int* __restrict__ rowptr,
                                            const int* __restrict__ adj,
                                            const float* __restrict__ att,
                                            const float* __restrict__ bias,
                                            const float* __restrict__ g,
                                            const float* __restrict__ be, int N) {
  int w = blockIdx.x * 4 + (threadIdx.x >> 6);
  int l = threadIdx.x & 63;
  if (w >= N) return;
  int sub = l & 15, strm = l >> 4;
  f16x8 xr8 = *(const f16x8*)(xr + (size_t)w * 128 + 8 * sub);
  const f16x2* xr2 = (const f16x2*)&xr8;
  f16x2 at2[4];
#pragma unroll
  for (int q = 0; q < 4; ++q) {
    at2[q][0] = (_Float16)att[8 * sub + 2 * q];
    at2[q][1] = (_Float16)att[8 * sub + 2 * q + 1];
  }
  float m = -1e30f, den = 0.f;
  f16x2 acc2[4];
#pragma unroll
  for (int q = 0; q < 4; ++q) { acc2[q][0] = (_Float16)0.f; acc2[q][1] = (_Float16)0.f; }
  int j0 = rowptr[w], j1 = rowptr[w + 1];

  auto proc = [&](f16x8 a8) {
    f16x8 av = a8;
    const f16x2* a2 = (const f16x2*)&av;
    float s = 0.f;
#pragma unroll
    for (int q = 0; q < 4; ++q) {
      f16x2 e = a2[q] + xr2[q];
      e = __builtin_elementwise_max(e, e * (_Float16)0.2f);
      s = __builtin_amdgcn_fdot2(e, at2[q], s, false);
    }
    s = dpp_add<0xB1>(s);  // xor1 (quad_perm)
    s = dpp_add<0x4E>(s);  // xor2
    float mn = fmaxf(m, s);
    float sa = __expf(m - mn), pb = __expf(s - mn);
    den = den * sa + pb;
    f16x2 sa2 = pkrtz(sa, sa);
    f16x2 pb2 = pkrtz(pb, pb);
#pragma unroll
    for (int q = 0; q < 4; ++q) acc2[q] = acc2[q] * sa2 + pb2 * a2[q];
    m = mn;
  };

  int j = j0 + strm;
  if (j < j1) {
    f16x8 a = *(const f16x8*)(xl + (size_t)adj[j] * 128 + 8 * sub);
    for (j += 4; j < j1; j += 4) {
      f16x8 an = *(const f16x8*)(xl + (size_t)adj[j] * 128 + 8 * sub);
      proc(a);
      a = an;
    }
    proc(a);
  }

  // merge 4 streams: xor16 (ds_swizzle), then xor32 (shfl)
  {
    float om = swz_f<0x401F>(m), oden = swz_f<0x401F>(den);
    f16x2 oa[4];
#pragma unroll
    for (int q = 0; q < 4; ++q) oa[q] = swz_h<0x401F>(acc2[q]);
    float mn = fmaxf(m, om);
    float sa = __expf(m - mn), sb = __expf(om - mn);
    den = den * sa + oden * sb;
    f16x2 sa2 = pkrtz(sa, sa);
    f16x2 sb2 = pkrtz(sb, sb);
#pragma unroll
    for (int q = 0; q < 4; ++q) acc2[q] = acc2[q] * sa2 + oa[q] * sb2;
    m = mn;
  }
  {
    float om = __shfl_xor(m, 32), oden = __shfl_xor(den, 32);
    f16x2 oa[4];
#pragma unroll
    for (int q = 0; q < 4; ++q) oa[q] = i2h(__shfl_xor(h2i(acc2[q]), 32));
    float mn = fmaxf(m, om);
    float sa = __expf(m - mn), sb = __expf(om - mn);
    den = den * sa + oden * sb;
    f16x2 sa2 = pkrtz(sa, sa);
    f16x2 sb2 = pkrtz(sb, sb);
#pragma unroll
    for (int q = 0; q < 4; ++q) acc2[q] = acc2[q] * sa2 + oa[q] * sb2;
    m = mn;
  }

  float inv = 1.f / (den + 1e-16f);
  float v[8], s1 = 0.f, s2 = 0.f;
#pragma unroll
  for (int q = 0; q < 4; ++q)
#pragma unroll
    for (int i = 0; i < 2; ++i) {
      int c = 2 * q + i;
      v[c] = (float)acc2[q][i] * inv + bias[8 * sub + c];
      s1 += v[c];
      s2 += v[c] * v[c];
    }
  s1 = dpp_add<0xB1>(s1); s2 = dpp_add<0xB1>(s2);
  s1 = dpp_add<0x4E>(s1); s2 = dpp_add<0x4E>(s2);
  s1 = swz_add<0x101F>(s1); s2 = swz_add<0x101F>(s2);  // xor4
  s1 = swz_add<0x201F>(s1); s2 = swz_add<0x201F>(s2);  // xor8
  float mu = s1 * (1.f / 128.f);
  float var = s2 * (1.f / 128.f) - mu * mu;
  float rs = rsqrtf(var + 1e-5f);
  if (strm == 0) {
    unsigned short o8[8];
#pragma unroll
    for (int c = 0; c < 8; ++c) {
      float r = (v[c] - mu) * rs * g[8 * sub + c] + be[8 * sub + c];
      r = r > 0.f ? r : expm1f(r);  // ELU
      o8[c] = f2bf(r);
    }
    *(uint4*)(h_out + (size_t)w * 128 + 8 * sub) = *(const uint4*)o8;
  }
}

// ---------------- fused GAT layer 2: wave/dst, 8 streams x 8 lanes, 8ch/lane ---------------
__global__ __launch_bounds__(256) void gat2(const _Float16* __restrict__ hl,
                                            const _Float16* __restrict__ hr,
                                            const int* __restrict__ rowptr,
                                            const int* __restrict__ adj,
                                            const float* __restrict__ att,
                                            const float* __restrict__ bias,
                                            const float* __restrict__ g,
                                            const float* __restrict__ be,
                                            _Float16* __restrict__ z, int N) {
  int w = blockIdx.x * 4 + (threadIdx.x >> 6);
  int l = threadIdx.x & 63;
  if (w >= N) return;
  int sub = l & 7, strm = l >> 3;
  f16x8 xr8 = *(const f16x8*)(hr + (size_t)w * 64 + 8 * sub);
  const f16x2* xr2 = (const f16x2*)&xr8;
  f16x2 at2[4];
#pragma unroll
  for (int q = 0; q < 4; ++q) {
    at2[q][0] = (_Float16)att[8 * sub + 2 * q];
    at2[q][1] = (_Float16)att[8 * sub + 2 * q + 1];
  }
  float m = -1e30f, den = 0.f;
  f16x2 acc2[4];
#pragma unroll
  for (int q = 0; q < 4; ++q) { acc2[q][0] = (_Float16)0.f; acc2[q][1] = (_Float16)0.f; }
  int j0 = rowptr[w], j1 = rowptr[w + 1];

  auto proc = [&](f16x8 a8) {
    f16x8 av = a8;
    const f16x2* a2 = (const f16x2*)&av;
    float s = 0.f;
#pragma unroll
    for (int q = 0; q < 4; ++q) {
      f16x2 e = a2[q] + xr2[q];
      e = __builtin_elementwise_max(e, e * (_Float16)0.2f);
      s = __builtin_amdgcn_fdot2(e, at2[q], s, false);
    }
    s = dpp_add<0xB1>(s);
    s = dpp_add<0x4E>(s);
    s = swz_add<0x101F>(s);  // xor4 -> full 64-ch logit within 8-lane group
    float mn = fmaxf(m, s);
    float sa = __expf(m - mn), pb = __expf(s - mn);
    den = den * sa + pb;
    f16x2 sa2 = pkrtz(sa, sa);
    f16x2 pb2 = pkrtz(pb, pb);
#pragma unroll
    for (int q = 0; q < 4; ++q) acc2[q] = acc2[q] * sa2 + pb2 * a2[q];
    m = mn;
  };

  int j = j0 + strm;
  if (j < j1) {
    f16x8 a = *(const f16x8*)(hl + (size_t)adj[j] * 64 + 8 * sub);
    for (j += 8; j < j1; j += 8) {
      f16x8 an = *(const f16x8*)(hl + (size_t)adj[j] * 64 + 8 * sub);
      proc(a);
      a = an;
    }
    proc(a);
  }

  // merge 8 streams: xor8, xor16 (swizzle), xor32 (shfl)
  {
    float om = swz_f<0x201F>(m), oden = swz_f<0x201F>(den);
    f16x2 oa[4];
#pragma unroll
    for (int q = 0; q < 4; ++q) oa[q] = swz_h<0x201F>(acc2[q]);
    float mn = fmaxf(m, om);
    float sa = __expf(m - mn), sb = __expf(om - mn);
    den = den * sa + oden * sb;
    f16x2 sa2 = pkrtz(sa, sa);
    f16x2 sb2 = pkrtz(sb, sb);
#pragma unroll
    for (int q = 0; q < 4; ++q) acc2[q] = acc2[q] * sa2 + oa[q] * sb2;
    m = mn;
  }
  {
    float om = swz_f<0x401F>(m), oden = swz_f<0x401F>(den);
    f16x2 oa[4];
#pragma unroll
    for (int q = 0; q < 4; ++q) oa[q] = swz_h<0x401F>(acc2[q]);
    float mn = fmaxf(m, om);
    float sa = __expf(m - mn), sb = __expf(om - mn);
    den = den * sa + oden * sb;
    f16x2 sa2 = pkrtz(sa, sa);
    f16x2 sb2 = pkrtz(sb, sb);
#pragma unroll
    for (int q = 0; q < 4; ++q) acc2[q] = acc2[q] * sa2 + oa[q] * sb2;
    m = mn;
  }
  {
    float om = __shfl_xor(m, 32), oden = __shfl_xor(den, 32);
    f16x2 oa[4];
#pragma unroll
    for (int q = 0; q < 4; ++q) oa[q] = i2h(__shfl_xor(h2i(acc2[q]), 32));
    float mn = fmaxf(m, om);
    float sa = __expf(m - mn), sb = __expf(om - mn);
    den = den * sa + oden * sb;
    f16x2 sa2 = pkrtz(sa, sa);
    f16x2 sb2 = pkrtz(sb, sb);
#pragma unroll
    for (int q = 0; q < 4; ++q) acc2[q] = acc2[q] * sa2 + oa[q] * sb2;
    m = mn;
  }

  float inv = 1.f / (den + 1e-16f);
  float v[8], s1 = 0.f, s2 = 0.f;
#pragma unroll
  for (int q = 0; q < 4; ++q)
#pragma unroll
    for (int i = 0; i < 2; ++i) {
      int c = 2 * q + i;
      v[c] = (float)acc2[q][i] * inv + bias[8 * sub + c];
      s1 += v[c];
      s2 += v[c] * v[c];
    }
  s1 = dpp_add<0xB1>(s1); s2 = dpp_add<0xB1>(s2);
  s1 = dpp_add<0x4E>(s1); s2 = dpp_add<0x4E>(s2);
  s1 = swz_add<0x101F>(s1); s2 = swz_add<0x101F>(s2);
  float mu = s1 * (1.f / 64.f);
  float var = s2 * (1.f / 64.f) - mu * mu;
  float rs = rsqrtf(var + 1e-5f);
  if (strm == 0) {
    f16x8 zz;
#pragma unroll
    for (int c = 0; c < 8; ++c)
      zz[c] = (_Float16)((v[c] - mu) * rs * g[8 * sub + c] + be[8 * sub + c]);
    *(f16x8*)(z + (size_t)w * 64 + 8 * sub) = zz;
  }
}

// ---------------- decode: 8 pairs per wave, 8 lanes per pair, fdot2 ----------------
__global__ __launch_bounds__(256) void decode(const _Float16* __restrict__ z,
                                              const int* __restrict__ eli,
                                              float* __restrict__ out, int EL) {
  int wv = threadIdx.x >> 6, l = threadIdx.x & 63;
  int sub = l & 7;
  int pidx = (blockIdx.x * 4 + wv) * 8 + (l >> 3);
  if (pidx >= EL) return;
  int a = eli[pidx], b = eli[EL + pidx];
  f16x8 za = *(const f16x8*)(z + (size_t)a * 64 + 8 * sub);
  f16x8 zb = *(const f16x8*)(z + (size_t)b * 64 + 8 * sub);
  const f16x2* za2 = (const f16x2*)&za;
  const f16x2* zb2 = (const f16x2*)&zb;
  float p = 0.f;
#pragma unroll
  for (int q = 0; q < 4; ++q) p = __builtin_amdgcn_fdot2(za2[q], zb2[q], p, false);
  p = dpp_add<0xB1>(p);
  p = dpp_add<0x4E>(p);
  p = swz_add<0x101F>(p);
  if (sub == 0) out[pidx] = p;
}

extern "C" void kernel_launch(void* const* d_in, const int* in_sizes, int n_in, void* d_out,
                              int out_size, void* d_ws, size_t ws_size, hipStream_t stream) {
  const float* x = (const float*)d_in[0];
  const int* ei = (const int*)d_in[1];
  const int* eli = (const int*)d_in[2];
  const float* W1l = (const float*)d_in[3];
  const float* b1l = (const float*)d_in[4];
  const float* W1r = (const float*)d_in[5];
  const float* b1r = (const float*)d_in[6];
  const float* att1 = (const float*)d_in[7];
  const float* bias1 = (const float*)d_in[8];
  const float* g1 = (const float*)d_in[9];
  const float* be1 = (const float*)d_in[10];
  const float* W2l = (const float*)d_in[11];
  const float* b2l = (const float*)d_in[12];
  const float* W2r = (const float*)d_in[13];
  const float* b2r = (const float*)d_in[14];
  const float* att2 = (const float*)d_in[15];
  const float* bias2 = (const float*)d_in[16];
  const float* g2 = (const float*)d_in[17];
  const float* be2 = (const float*)d_in[18];

  const int N = in_sizes[0] / 128;
  const int E = in_sizes[1] / 2;
  const int EL = in_sizes[2] / 2;
  const int ET = E + N;

  char* base = (char*)d_ws;
  _Float16* xl16 = (_Float16*)base;                                  // N*128 f16
  _Float16* xr16 = (_Float16*)(base + (size_t)N * 256);              // N*128 f16
  unsigned short* h_bf = (unsigned short*)(base + (size_t)N * 512);  // N*128 bf16
  _Float16* hl16 = (_Float16*)(base + (size_t)N * 768);              // N*64 f16
  _Float16* hr16 = (_Float16*)(base + (size_t)N * 896);              // N*64 f16
  _Float16* z16 = (_Float16*)(base + (size_t)N * 1024);              // N*64 f16
  int* ib = (int*)(base + (size_t)N * 1152);
  int* cnt = ib;
  int* cur = ib + N;
  int* rowptr = ib + 2 * N;
  int* part = ib + 3 * N + 2;
  int* adj = ib + 3 * N + 258;
  size_t ints_bytes = ((size_t)(3 * N + 258) + (size_t)ET) * 4;
  unsigned short* wbuf =
      (unsigned short*)(base + (((size_t)N * 1152 + ints_bytes + 255) & ~(size_t)255));

  hipMemsetAsync(cnt, 0, 2 * N * sizeof(int), stream);
  prep_w<<<64, 256, 0, stream>>>(W1l, W1r, W2l, W2r, wbuf);

  const int Mtiles = (N + 15) / 16;
  const int pBlocks = ((Mtiles + 1) / 2 + 3) / 4;
  proj_mfma<float, 128><<<pBlocks, 256, 0, stream>>>(x, wbuf, b1l, b1r, xl16, xr16, Mtiles);

  const int eB = (ET + 255) / 256;
  const int nB = (N + 255) / 256;
  deg_count<<<eB, 256, 0, stream>>>(ei, cnt, E, ET);
  scanA<<<nB, 256, 0, stream>>>(cnt, part, N);
  scanB<<<1, 256, 0, stream>>>(part, rowptr, nB, N);
  scanC<<<nB, 256, 0, stream>>>(cnt, part, rowptr, N);
  scatter_e<<<eB, 256, 0, stream>>>(ei, rowptr, cur, adj, E, ET);

  const int gB = (N + 3) / 4;
  gat1<<<gB, 256, 0, stream>>>(xl16, xr16, h_bf, rowptr, adj, att1, bias1, g1, be1, N);

  proj_mfma<unsigned short, 64>
      <<<pBlocks, 256, 0, stream>>>(h_bf, wbuf + 32768, b2l, b2r, hl16, hr16, Mtiles);

  gat2<<<gB, 256, 0, stream>>>(hl16, hr16, rowptr, adj, att2, bias2, g2, be2, z16, N);

  const int dBlocks = (EL + 31) / 32;
  decode<<<dBlocks, 256, 0, stream>>>(z16, eli, (float*)d_out, EL);
}